// Round 19
// baseline (1650.414 us; speedup 1.0000x reference)
//
#include <hip/hip_runtime.h>
#include <hip/hip_bf16.h>

#define NLOW  8000
#define NHIGH 50000
#define NL25  200000
#define ELL   32000
#define ELH   1250000
#define EHH   800000
#define LOG2E 1.4426950408889634f

__global__ void k_fill_out(float* __restrict__ o, int n, float v) {
  int i = blockIdx.x * 256 + threadIdx.x;
  if (i < n) o[i] = v;
}

// ---------------- Stage 1: fused GCN ----------------
__global__ void k_init_deg(float* __restrict__ deg) {
  int i = blockIdx.x * 256 + threadIdx.x;
  if (i < NLOW) deg[i] = 1.0f;
}
__global__ void k_gcn_deg(const int* __restrict__ ei, float* __restrict__ deg) {
  int e = blockIdx.x * 256 + threadIdx.x;
  if (e >= ELL) return;
  int d = ei[ELL + e];
  if (d >= 0 && d < NLOW) atomicAdd(&deg[d], 1.0f);
}
__global__ void k_xa_init(const float* __restrict__ x, const float* __restrict__ deg,
                          float* __restrict__ xa) {
  int i = blockIdx.x * 256 + threadIdx.x;
  if (i >= NLOW * 125) return;
  xa[i] = x[i] / deg[i / 125];
}
__global__ void k_xa_edge(const float* __restrict__ x, const int* __restrict__ ei,
                          const float* __restrict__ deg, float* __restrict__ xa) {
  int gid = blockIdx.x * 256 + threadIdx.x;
  if (gid >= ELL * 125) return;
  int e = gid / 125, k = gid - e * 125;
  int s = ei[e], d = ei[ELL + e];
  if (s < 0 || s >= NLOW || d < 0 || d >= NLOW) return;
  float nrm = rsqrtf(deg[s]) * rsqrtf(deg[d]);
  atomicAdd(&xa[d * 125 + k], nrm * x[s * 125 + k]);
}
__global__ void k_prep_M(const float* __restrict__ W, const float* __restrict__ Wl,
                         float* __restrict__ M) {
  int gid = blockIdx.x * 256 + threadIdx.x;
  if (gid >= 125 * 2500) return;
  int vk = gid / 2500, r = gid - vk * 2500, sp = r / 100, j = r - sp * 100;
  int v = vk / 25;
  float acc = 0.f;
#pragma unroll
  for (int c = 0; c < 25; c++)
    acc = fmaf(W[vk * 625 + c * 25 + sp], Wl[(v * 25 + c) * 100 + j], acc);
  M[gid] = acc;
}
__global__ void k_prep_b2(const float* __restrict__ b, const float* __restrict__ Wl,
                          const float* __restrict__ bl, float* __restrict__ b2) {
  int gid = blockIdx.x * 256 + threadIdx.x;
  if (gid >= 2500) return;
  int sp = gid / 100, j = gid - sp * 100;
  float acc = bl[j];
  for (int v = 0; v < 5; v++)
#pragma unroll
    for (int c = 0; c < 25; c++)
      acc = fmaf(b[v * 625 + c * 25 + sp], Wl[(v * 25 + c) * 100 + j], acc);
  b2[gid] = acc;
}

// Tiled GEMM -> bf16 hl100, head-pair interleaved.
__global__ void k_hlT_gemm(const float* __restrict__ A, const float* __restrict__ M,
                           const float* __restrict__ b2v,
                           unsigned short* __restrict__ out16) {
  __shared__ float As[32 * 68];
  __shared__ float Bs[32 * 68];
  int t = threadIdx.x;
  int tx = t & 15, ty = t >> 4;
  int row0 = blockIdx.x * 64, col0 = blockIdx.y * 64;
  float acc[4][4];
#pragma unroll
  for (int i = 0; i < 4; i++)
#pragma unroll
    for (int j = 0; j < 4; j++) acc[i][j] = 0.f;
  for (int k0 = 0; k0 < 125; k0 += 32) {
    int kw = 125 - k0; if (kw > 32) kw = 32;
    for (int l = t; l < 64 * 32; l += 256) {
      int r = l >> 5, kk = l & 31;
      As[kk * 68 + r] = (kk < kw) ? A[(size_t)(row0 + r) * 125 + k0 + kk] : 0.f;
    }
    for (int l = t; l < 32 * 64; l += 256) {
      int kk = l >> 6, bb = l & 63;
      int b = col0 + bb;
      float v = 0.f;
      if (kk < kw && b < 2500) {
        int sp = b / 100, r = b - sp * 100;
        int g = r / 50, q = r - g * 50, cc = q >> 1, hp = q & 1;
        int cm = sp * 100 + (2 * g + hp) * 25 + cc;
        v = M[(size_t)(k0 + kk) * 2500 + cm];
      }
      Bs[kk * 68 + bb] = v;
    }
    __syncthreads();
#pragma unroll 8
    for (int kk = 0; kk < 32; kk++) {
      float4 a4 = *(const float4*)&As[kk * 68 + ty * 4];
      float4 b4 = *(const float4*)&Bs[kk * 68 + tx * 4];
      float a[4] = {a4.x, a4.y, a4.z, a4.w};
      float b[4] = {b4.x, b4.y, b4.z, b4.w};
#pragma unroll
      for (int i = 0; i < 4; i++)
#pragma unroll
        for (int j = 0; j < 4; j++) acc[i][j] = fmaf(a[i], b[j], acc[i][j]);
    }
    __syncthreads();
  }
#pragma unroll
  for (int i = 0; i < 4; i++) {
    int r = row0 + ty * 4 + i;
#pragma unroll
    for (int j = 0; j < 4; j++) {
      int b = col0 + tx * 4 + j;
      if (b < 2500) {
        int sp = b / 100, rr = b - sp * 100;
        int g = rr / 50, q = rr - g * 50, cc = q >> 1, hp = q & 1;
        int cm = sp * 100 + (2 * g + hp) * 25 + cc;
        __hip_bfloat16 hv = __float2bfloat16(acc[i][j] + b2v[cm]);
        out16[(size_t)r * 2500 + b] = *(unsigned short*)&hv;
      }
    }
  }
}

// ---- Generic 64x64-tile GEMM, fused BN(+ReLU) on input, ReLU on out ----
template <int CIN, bool BN, bool INRELU, bool OUTRELU>
__global__ void k_gemm_lin(const float* __restrict__ X, const float* __restrict__ sc,
                           const float* __restrict__ sh, const float* __restrict__ W,
                           const float* __restrict__ bias, float* __restrict__ out,
                           int n, int COUT) {
  __shared__ float As[32 * 68];
  __shared__ float Bs[32 * 68];
  int t = threadIdx.x;
  int tx = t & 15, ty = t >> 4;
  int row0 = blockIdx.x * 64, col0 = blockIdx.y * 64;
  float acc[4][4];
#pragma unroll
  for (int i = 0; i < 4; i++)
#pragma unroll
    for (int j = 0; j < 4; j++) acc[i][j] = 0.f;
  for (int k0 = 0; k0 < CIN; k0 += 32) {
    int kw = CIN - k0; if (kw > 32) kw = 32;
    for (int l = t; l < 64 * 32; l += 256) {
      int r = l >> 5, kk = l & 31;
      float v = 0.f;
      int rr = row0 + r;
      if (kk < kw && rr < n) {
        int k = k0 + kk;
        v = X[(size_t)rr * CIN + k];
        if (BN) v = fmaf(v, sc[k], sh[k]);
        if (INRELU) v = fmaxf(v, 0.f);
      }
      As[kk * 68 + r] = v;
    }
    for (int l = t; l < 32 * 64; l += 256) {
      int kk = l >> 6, cc = l & 63;
      Bs[kk * 68 + cc] = (kk < kw) ? W[(size_t)(k0 + kk) * COUT + col0 + cc] : 0.f;
    }
    __syncthreads();
#pragma unroll 8
    for (int kk = 0; kk < 32; kk++) {
      float4 a4 = *(const float4*)&As[kk * 68 + ty * 4];
      float4 b4 = *(const float4*)&Bs[kk * 68 + tx * 4];
      float a[4] = {a4.x, a4.y, a4.z, a4.w};
      float b[4] = {b4.x, b4.y, b4.z, b4.w};
#pragma unroll
      for (int i = 0; i < 4; i++)
#pragma unroll
        for (int j = 0; j < 4; j++) acc[i][j] = fmaf(a[i], b[j], acc[i][j]);
    }
    __syncthreads();
  }
#pragma unroll
  for (int i = 0; i < 4; i++) {
    int r = row0 + ty * 4 + i;
    if (r >= n) continue;
#pragma unroll
    for (int j = 0; j < 4; j++) {
      int c = col0 + tx * 4 + j;
      float v = acc[i][j] + bias[c];
      if (OUTRELU) v = fmaxf(v, 0.f);
      out[(size_t)r * COUT + c] = v;
    }
  }
}

// ---------------- CSR build ----------------
__global__ void k_hist(const int* __restrict__ dst, int E, int* __restrict__ cnt) {
  int e = blockIdx.x * 256 + threadIdx.x;
  if (e >= E) return;
  int d = dst[e];
  if (d >= 0 && d < NHIGH) atomicAdd(&cnt[d], 1);
}
__global__ void k_scan1(const int* __restrict__ cnt, int* __restrict__ rp,
                        int* __restrict__ part, int N) {
  __shared__ int sh[256];
  int i = blockIdx.x * 256 + threadIdx.x;
  int v = (i < N) ? cnt[i] : 0;
  sh[threadIdx.x] = v;
  __syncthreads();
  for (int off = 1; off < 256; off <<= 1) {
    int t = (threadIdx.x >= off) ? sh[threadIdx.x - off] : 0;
    __syncthreads();
    sh[threadIdx.x] += t;
    __syncthreads();
  }
  if (i < N) rp[i] = sh[threadIdx.x] - v;
  if (threadIdx.x == 255) part[blockIdx.x] = sh[255];
}
__global__ void k_scan2(int* __restrict__ part, int nb) {
  __shared__ int sh[256];
  int v = (threadIdx.x < nb) ? part[threadIdx.x] : 0;
  sh[threadIdx.x] = v;
  __syncthreads();
  for (int off = 1; off < 256; off <<= 1) {
    int t = (threadIdx.x >= off) ? sh[threadIdx.x - off] : 0;
    __syncthreads();
    sh[threadIdx.x] += t;
    __syncthreads();
  }
  if (threadIdx.x < nb) part[threadIdx.x] = sh[threadIdx.x] - v;
}
__global__ void k_scan3(int* __restrict__ rp, const int* __restrict__ part, int N, int E) {
  int i = blockIdx.x * 256 + threadIdx.x;
  if (i < N) rp[i] += part[i / 256];
  if (i == 0) rp[N] = E;
}
__global__ void k_csr_scatter(const int* __restrict__ src, const int* __restrict__ dst,
                              const int* __restrict__ rp, int* __restrict__ fil,
                              int* __restrict__ col, int E) {
  int e = blockIdx.x * 256 + threadIdx.x;
  if (e >= E) return;
  int d = dst[e];
  if (d < 0 || d >= NHIGH) return;
  int pos = rp[d] + atomicAdd(&fil[d], 1);
  if (pos >= 0 && pos < E) col[pos] = src[e];
}

// ---------------- Stage 2: bipartite GATv2 (4 nodes/block, 1 wave each) ----------------
__global__ void k_gat_th(const unsigned* __restrict__ hlu, const float* __restrict__ z,
                         const float* __restrict__ wr, const float* __restrict__ br,
                         const float* __restrict__ att, const int* __restrict__ rp,
                         const int* __restrict__ col, float* __restrict__ acc25) {
  int d = blockIdx.x * 4 + (threadIdx.x >> 6);
  if (d >= NHIGH) return;
  int lane = threadIdx.x & 63;
  int beg = rp[d];
  int deg = rp[d + 1] - beg;
  if (beg < 0) beg = 0;
  if (deg < 0) deg = 0;
  if (beg + deg > ELH) deg = (ELH - beg > 0) ? (ELH - beg) : 0;
  float zd = z[d];
  int g = lane >> 5, cc = lane & 31;
  bool act = cc < 25;
  int j0 = 50 * g + (act ? cc : 0), j1 = j0 + 25;
  float hrv0 = 0.f, atv0 = 0.f, hrv1 = 0.f, atv1 = 0.f;
  if (act) {
    hrv0 = fmaf(zd, wr[j0], br[j0]); atv0 = att[j0] * LOG2E;
    hrv1 = fmaf(zd, wr[j1], br[j1]); atv1 = att[j1] * LOG2E;
  }
  bool hi = (lane & 16) != 0;
  float den0 = 0.f, a0 = 0.f, den1 = 0.f, a1 = 0.f;
  int i = 0;
  for (; i + 2 <= deg; i += 2) {
    int sA = col[beg + i];
    int sB = col[beg + i + 1];
    if (sA < 0 || sA >= NL25) sA = 0;
    if (sB < 0 || sB >= NL25) sB = 0;
    unsigned uA = act ? hlu[(size_t)sA * 50 + g * 25 + cc] : 0u;
    unsigned uB = act ? hlu[(size_t)sB * 50 + g * 25 + cc] : 0u;
    float r0a = __uint_as_float(uA << 16), r1a = __uint_as_float(uA & 0xffff0000u);
    float r0b = __uint_as_float(uB << 16), r1b = __uint_as_float(uB & 0xffff0000u);
    float e0a = r0a + hrv0; e0a = (e0a > 0.f) ? e0a : 0.2f * e0a;
    float e1a = r1a + hrv1; e1a = (e1a > 0.f) ? e1a : 0.2f * e1a;
    float e0b = r0b + hrv0; e0b = (e0b > 0.f) ? e0b : 0.2f * e0b;
    float e1b = r1b + hrv1; e1b = (e1b > 0.f) ? e1b : 0.2f * e1b;
    float p0a = e0a * atv0, p1a = e1a * atv1;
    float p0b = e0b * atv0, p1b = e1b * atv1;
    float qa = (hi ? p1a : p0a) + __shfl_xor(hi ? p0a : p1a, 16, 64);
    float qb = (hi ? p1b : p0b) + __shfl_xor(hi ? p0b : p1b, 16, 64);
#pragma unroll
    for (int off = 8; off > 0; off >>= 1) {
      qa += __shfl_xor(qa, off, 64);
      qb += __shfl_xor(qb, off, 64);
    }
    float oa = __shfl_xor(qa, 16, 64);
    float ob = __shfl_xor(qb, 16, 64);
    p0a = hi ? oa : qa; p1a = hi ? qa : oa;
    p0b = hi ? ob : qb; p1b = hi ? qb : ob;
    float w0a = exp2f(p0a), w1a = exp2f(p1a);
    float w0b = exp2f(p0b), w1b = exp2f(p1b);
    den0 += w0a + w0b;
    den1 += w1a + w1b;
    a0 = fmaf(w0a, r0a, a0); a0 = fmaf(w0b, r0b, a0);
    a1 = fmaf(w1a, r1a, a1); a1 = fmaf(w1b, r1b, a1);
  }
  if (i < deg) {
    int s = col[beg + i];
    if (s < 0 || s >= NL25) s = 0;
    unsigned u = act ? hlu[(size_t)s * 50 + g * 25 + cc] : 0u;
    float r0 = __uint_as_float(u << 16);
    float r1 = __uint_as_float(u & 0xffff0000u);
    float e0 = r0 + hrv0; e0 = (e0 > 0.f) ? e0 : 0.2f * e0;
    float e1 = r1 + hrv1; e1 = (e1 > 0.f) ? e1 : 0.2f * e1;
    float p0 = e0 * atv0, p1 = e1 * atv1;
    float q = (hi ? p1 : p0) + __shfl_xor(hi ? p0 : p1, 16, 64);
#pragma unroll
    for (int off = 8; off > 0; off >>= 1) q += __shfl_xor(q, off, 64);
    float o = __shfl_xor(q, 16, 64);
    p0 = hi ? o : q;
    p1 = hi ? q : o;
    float w0 = exp2f(p0), w1 = exp2f(p1);
    den0 += w0; a0 = fmaf(w0, r0, a0);
    den1 += w1; a1 = fmaf(w1, r1, a1);
  }
  float v = a0 / fmaxf(den0, 1e-30f) + a1 / fmaxf(den1, 1e-30f);
  float other = __shfl_down(v, 32, 64);
  if (lane < 25) acc25[d * 25 + lane] = v + other;
}
__global__ void k_th_fin(const float* __restrict__ acc25, const int* __restrict__ rp,
                         const float* __restrict__ bias, const float* __restrict__ z,
                         float* __restrict__ x26) {
  int gid = blockIdx.x * 256 + threadIdx.x;
  int node = gid / 26, j = gid - node * 26;
  if (node >= NHIGH) return;
  if (j == 0) {
    x26[node * 26] = z[node];
  } else {
    int dg = rp[node + 1] - rp[node];
    if (dg < 1) dg = 1;
    x26[node * 26 + j] = acc25[node * 25 + j - 1] / (4.0f * (float)dg) + bias[j - 1];
  }
}

// ---------------- high-res GATv2 (4 nodes/block, 1 wave each) ----------------
template <bool RELU>
__global__ void k_gat_hh2(const float* __restrict__ hl, const float* __restrict__ hr,
                          const float* __restrict__ att, const float* __restrict__ bias,
                          const int* __restrict__ rp, const int* __restrict__ col,
                          float* __restrict__ out) {
  const int F = 128;
  int d = blockIdx.x * 4 + (threadIdx.x >> 6);
  if (d >= NHIGH) return;
  int lane = threadIdx.x & 63;
  int h = lane >> 5, l2 = lane & 31;
  int c0 = h * 64 + 2 * l2;
  int beg = rp[d];
  int deg = rp[d + 1] - beg;
  if (beg < 0) beg = 0;
  if (deg < 0) deg = 0;
  if (beg + deg > EHH) deg = (EHH - beg > 0) ? (EHH - beg) : 0;
  int tot = deg + 1;  // + self loop
  float2 hrv = *(const float2*)&hr[(size_t)d * F + c0];
  float2 atv = *(const float2*)&att[c0];
  atv.x *= LOG2E; atv.y *= LOG2E;
  bool hi = (lane & 16) != 0;
  float den = 0.f, acc0 = 0.f, acc1 = 0.f;
  int i = 0;
  for (; i + 2 <= tot; i += 2) {
    int sA = (i < deg) ? col[beg + i] : d;
    int sB = (i + 1 < deg) ? col[beg + i + 1] : d;
    if (sA < 0 || sA >= NHIGH) sA = 0;
    if (sB < 0 || sB >= NHIGH) sB = 0;
    float2 ra = *(const float2*)&hl[(size_t)sA * F + c0];
    float2 rb = *(const float2*)&hl[(size_t)sB * F + c0];
    float e0a = ra.x + hrv.x; e0a = (e0a > 0.f) ? e0a : 0.2f * e0a;
    float e1a = ra.y + hrv.y; e1a = (e1a > 0.f) ? e1a : 0.2f * e1a;
    float pA = fmaf(e0a, atv.x, e1a * atv.y);
    float e0b = rb.x + hrv.x; e0b = (e0b > 0.f) ? e0b : 0.2f * e0b;
    float e1b = rb.y + hrv.y; e1b = (e1b > 0.f) ? e1b : 0.2f * e1b;
    float pB = fmaf(e0b, atv.x, e1b * atv.y);
    float own = hi ? pB : pA;
    float oth = hi ? pA : pB;
    float q = own + __shfl_xor(oth, 16, 64);
#pragma unroll
    for (int off = 8; off > 0; off >>= 1) q += __shfl_xor(q, off, 64);
    float o = __shfl_xor(q, 16, 64);
    pA = hi ? o : q;
    pB = hi ? q : o;
    float wA = exp2f(pA), wB = exp2f(pB);
    den += wA + wB;
    acc0 = fmaf(wA, ra.x, acc0); acc0 = fmaf(wB, rb.x, acc0);
    acc1 = fmaf(wA, ra.y, acc1); acc1 = fmaf(wB, rb.y, acc1);
  }
  if (i < tot) {
    int s = (i < deg) ? col[beg + i] : d;
    if (s < 0 || s >= NHIGH) s = 0;
    float2 r = *(const float2*)&hl[(size_t)s * F + c0];
    float e0 = r.x + hrv.x; e0 = (e0 > 0.f) ? e0 : 0.2f * e0;
    float e1 = r.y + hrv.y; e1 = (e1 > 0.f) ? e1 : 0.2f * e1;
    float p = fmaf(e0, atv.x, e1 * atv.y);
#pragma unroll
    for (int off = 16; off > 0; off >>= 1) p += __shfl_xor(p, off, 64);
    float w_ = exp2f(p);
    den += w_;
    acc0 = fmaf(w_, r.x, acc0);
    acc1 = fmaf(w_, r.y, acc1);
  }
  float inv = 1.0f / (fmaxf(den, 1e-30f) * (float)tot);
  float2 bv = *(const float2*)&bias[c0];
  float v0 = acc0 * inv + bv.x;
  float v1 = acc1 * inv + bv.y;
  if (RELU) { v0 = fmaxf(v0, 0.f); v1 = fmaxf(v1, 0.f); }
  *(float2*)&out[(size_t)d * F + c0] = make_float2(v0, v1);
}
template <bool RELU>
__global__ void k_gat_hh1(const float* __restrict__ hl, const float* __restrict__ hr,
                          const float* __restrict__ att, const float* __restrict__ bias,
                          const int* __restrict__ rp, const int* __restrict__ col,
                          float* __restrict__ out) {
  const int F = 64;
  int d = blockIdx.x * 4 + (threadIdx.x >> 6);
  if (d >= NHIGH) return;
  int lane = threadIdx.x & 63;
  int beg = rp[d];
  int deg = rp[d + 1] - beg;
  if (beg < 0) beg = 0;
  if (deg < 0) deg = 0;
  if (beg + deg > EHH) deg = (EHH - beg > 0) ? (EHH - beg) : 0;
  int tot = deg + 1;
  float hrv = hr[(size_t)d * F + lane];
  float atv = att[lane] * LOG2E;
  bool hi = lane >= 32;
  float den = 0.f, acc = 0.f;
  int i = 0;
  for (; i + 2 <= tot; i += 2) {
    int sA = (i < deg) ? col[beg + i] : d;
    int sB = (i + 1 < deg) ? col[beg + i + 1] : d;
    if (sA < 0 || sA >= NHIGH) sA = 0;
    if (sB < 0 || sB >= NHIGH) sB = 0;
    float rA = hl[(size_t)sA * F + lane];
    float rB = hl[(size_t)sB * F + lane];
    float eA = rA + hrv; eA = (eA > 0.f) ? eA : 0.2f * eA;
    float eB = rB + hrv; eB = (eB > 0.f) ? eB : 0.2f * eB;
    float pA = eA * atv, pB = eB * atv;
    float own = hi ? pB : pA;
    float oth = hi ? pA : pB;
    float q = own + __shfl_xor(oth, 32, 64);
#pragma unroll
    for (int off = 16; off > 0; off >>= 1) q += __shfl_xor(q, off, 64);
    float o = __shfl_xor(q, 32, 64);
    pA = hi ? o : q;
    pB = hi ? q : o;
    float wA = exp2f(pA), wB = exp2f(pB);
    den += wA + wB;
    acc = fmaf(wA, rA, acc);
    acc = fmaf(wB, rB, acc);
  }
  if (i < tot) {
    int s = (i < deg) ? col[beg + i] : d;
    if (s < 0 || s >= NHIGH) s = 0;
    float r = hl[(size_t)s * F + lane];
    float e = r + hrv; e = (e > 0.f) ? e : 0.2f * e;
    float p = e * atv;
#pragma unroll
    for (int off = 32; off > 0; off >>= 1) p += __shfl_xor(p, off, 64);
    float w_ = exp2f(p);
    den += w_;
    acc = fmaf(w_, r, acc);
  }
  float v = acc / (fmaxf(den, 1e-30f) * (float)tot) + bias[lane];
  if (RELU) v = fmaxf(v, 0.f);
  out[(size_t)d * F + lane] = v;
}

// ---------------- BatchNorm: parallel partials + f64 finalize -> scale/shift ----------------
__global__ void k_bn_part(const float* __restrict__ x, int C, int tpc,
                          float* __restrict__ ps, float* __restrict__ ps2) {
  int gch = blockIdx.x, t = threadIdx.x;
  int c = t % C, sub = t / C;
  float s = 0.f, s2 = 0.f;
  if (sub < tpc) {
    for (int r = gch * 500 + sub; r < gch * 500 + 500; r += tpc) {
      float v = x[(size_t)r * C + c];
      s += v;
      s2 = fmaf(v, v, s2);
    }
  }
  __shared__ float ls[256], ls2[256];
  ls[t] = s; ls2[t] = s2;
  __syncthreads();
  if (t < C) {
    float a = 0.f, a2 = 0.f;
    for (int u = 0; u < tpc; u++) { a += ls[u * C + t]; a2 += ls2[u * C + t]; }
    ps[gch * C + t] = a;
    ps2[gch * C + t] = a2;
  }
}
__global__ void k_bn_fin(const float* __restrict__ ps, const float* __restrict__ ps2,
                         int C, float n, const float* __restrict__ g,
                         const float* __restrict__ b, float* __restrict__ sc,
                         float* __restrict__ sh) {
  int c = blockIdx.x, t = threadIdx.x;
  __shared__ double ds[128], ds2[128];
  double a = 0, a2 = 0;
  for (int q = t; q < 100; q += 128) { a += ps[q * C + c]; a2 += ps2[q * C + c]; }
  ds[t] = a; ds2[t] = a2;
  __syncthreads();
  for (int off = 64; off > 0; off >>= 1) {
    if (t < off) { ds[t] += ds[t + off]; ds2[t] += ds2[t + off]; }
    __syncthreads();
  }
  if (t == 0) {
    double m = ds[0] / n;
    double v = ds2[0] / n - m * m;
    if (v < 0) v = 0;
    float scale = g[c] * rsqrtf((float)v + 1e-5f);
    sc[c] = scale;
    sh[c] = b[c] - (float)m * scale;
  }
}

// small naive linear for MLP tails
template <int CIN, int COUT, bool RELU>
__global__ void k_linear(const float* __restrict__ x, const float* __restrict__ W,
                         const float* __restrict__ b, float* __restrict__ y, int n) {
  long long gid = (long long)blockIdx.x * 256 + threadIdx.x;
  int node = (int)(gid / COUT);
  int j = (int)(gid - (long long)node * COUT);
  if (node >= n) return;
  const float* xr = x + (size_t)node * CIN;
  float acc = b[j];
#pragma unroll 4
  for (int k = 0; k < CIN; k++) acc = fmaf(xr[k], W[k * COUT + j], acc);
  if (RELU) acc = fmaxf(acc, 0.f);
  y[(size_t)node * COUT + j] = acc;
}

extern "C" void kernel_launch(void* const* d_in, const int* in_sizes, int n_in,
                              void* d_out, int out_size, void* d_ws, size_t ws_size,
                              hipStream_t stream) {
  auto nb = [](long long t) { return dim3((unsigned)((t + 255) / 256)); };
  static const int FSZ[38] = {
      1000000, 50000, 78125, 3125, 12500, 100, 100, 100, 100, 25, 26, 26,
      3328, 128, 3328, 128, 128, 128, 512, 512, 49152, 384, 49152, 384, 384,
      384, 8192, 64, 8192, 64, 64, 64, 4096, 64, 2048, 32, 32, 1};
  static const int ISZ[4] = {64000, 1250000, 1250000, 1600000};
  if (n_in != 42) {
    k_fill_out<<<nb(out_size), 256, 0, stream>>>((float*)d_out, out_size, 500000.0f);
    return;
  }
  bool szok = true;
  for (int i = 0; i < 38; i++) szok &= (in_sizes[i] == FSZ[i]);
  for (int i = 0; i < 4; i++) szok &= (in_sizes[38 + i] == ISZ[i]);
  if (!szok) {
    k_fill_out<<<nb(out_size), 256, 0, stream>>>((float*)d_out, out_size, 600000.0f);
    return;
  }
  const size_t REQUIRED = 20146000ull * 4ull;
  if (ws_size < REQUIRED) {
    hipMemsetAsync(d_out, 0, (size_t)out_size * 4, stream);
    return;
  }

  const float* w[38];
  for (int i = 0; i < 38; i++) w[i] = (const float*)d_in[i];  // f32 (verified r6/r9)
  const int* ei_ll = (const int*)d_in[38];  // int32 (verified r9/r10)
  const int* s_l2h = (const int*)d_in[39];
  const int* d_l2h = (const int*)d_in[40];
  const int* ei_hh = (const int*)d_in[41];

  float* ws = (float*)d_ws;
  float* S0 = ws;                       // [0, 6.4M)
  float* S1 = ws + 6400000;             // [6.4M, 12.8M)
  float* S2 = ws + 12800000;            // [12.8M, 19.2M)
  unsigned short* hl100 = (unsigned short*)ws;  // [20M bf16] = 10M words
  float* acc25 = ws + 10000000;         // [1,250,000]
  int*  rpT  = (int*)(ws + 11300000);   // [50,001]
  int*  filT = (int*)(ws + 11360000);   // [50,000]
  int*  colT = (int*)(ws + 11450000);   // [1,250,000] -> 12.7M
  float* xa  = ws + 12800000;           // [1,000,000]
  float* Mt  = ws + 13800000;           // [312,500]
  float* b2  = ws + 14112500;           // [2,500]
  float* x26 = ws + 14200000;           // [1,300,000] (dead before S2 written)
  int*  rpH  = (int*)(ws + 19200000);   // [50,001]
  int*  filH = (int*)(ws + 19260000);   // [50,000]
  int*  colH = (int*)(ws + 19310000);   // [800,000] -> 20,110,000
  float* deg = ws + 20110000;           // [8,000]
  float* sc  = ws + 20118000;           // [128]
  float* sh  = ws + 20118128;           // [128]
  int*  part = (int*)(ws + 20118256);   // [512]
  float* ps   = ws + 20120000;          // [12,800]
  float* ps2  = ws + 20132800;          // [12,800] -> 20,145,600

  // ---- CSR for both graphs ----
  auto build_csr = [&](const int* src, const int* dst, int E, int* rp, int* fil,
                       int* col) {
    hipMemsetAsync(fil, 0, NHIGH * 4, stream);
    k_hist<<<nb(E), 256, 0, stream>>>(dst, E, fil);
    int nblk = (NHIGH + 255) / 256;
    k_scan1<<<nblk, 256, 0, stream>>>(fil, rp, part, NHIGH);
    k_scan2<<<1, 256, 0, stream>>>(part, nblk);
    k_scan3<<<nb(NHIGH), 256, 0, stream>>>(rp, part, NHIGH, E);
    hipMemsetAsync(fil, 0, NHIGH * 4, stream);
    k_csr_scatter<<<nb(E), 256, 0, stream>>>(src, dst, rp, fil, col, E);
  };
  build_csr(s_l2h, d_l2h, ELH, rpT, filT, colT);
  build_csr(ei_hh, ei_hh + EHH, EHH, rpH, filH, colH);

  // ---- Stage 1: GCN fold ----
  k_init_deg<<<nb(NLOW), 256, 0, stream>>>(deg);
  k_gcn_deg<<<nb(ELL), 256, 0, stream>>>(ei_ll, deg);
  k_xa_init<<<nb(NLOW * 125), 256, 0, stream>>>(w[0], deg, xa);
  k_xa_edge<<<nb((long long)ELL * 125), 256, 0, stream>>>(w[0], ei_ll, deg, xa);
  k_prep_M<<<nb(125 * 2500), 256, 0, stream>>>(w[2], w[4], Mt);
  k_prep_b2<<<nb(2500), 256, 0, stream>>>(w[3], w[4], w[5], b2);

  // ---- Stage 2: th GATv2, single fused pass ----
  k_hlT_gemm<<<dim3(125, 40), 256, 0, stream>>>(xa, Mt, b2, hl100);
  k_gat_th<<<12500, 256, 0, stream>>>((const unsigned*)hl100, w[1], w[6], w[7], w[8],
                                      rpT, colT, acc25);
  k_th_fin<<<nb((long long)NHIGH * 26), 256, 0, stream>>>(acc25, rpT, w[9], w[1], x26);

  const dim3 g1(782, 2), g2(782, 1);

  // ---- Stage 3: bn0 + g1 ----
  k_bn_part<<<100, 256, 0, stream>>>(x26, 26, 9, ps, ps2);
  k_bn_fin<<<26, 128, 0, stream>>>(ps, ps2, 26, (float)NHIGH, w[10], w[11], sc, sh);
  k_gemm_lin<26, true, false, false><<<g1, 256, 0, stream>>>(
      x26, sc, sh, w[12], w[13], S0, NHIGH, 128);
  k_gemm_lin<26, true, false, false><<<g1, 256, 0, stream>>>(
      x26, sc, sh, w[14], w[15], S1, NHIGH, 128);
  k_gat_hh2<false><<<12500, 256, 0, stream>>>(S0, S1, w[16], w[17], rpH, colH, S2);

  // ---- Stage 4: 3x gm ----
  for (int i = 0; i < 3; i++) {
    k_bn_part<<<100, 256, 0, stream>>>(S2, 128, 2, ps, ps2);
    k_bn_fin<<<128, 128, 0, stream>>>(ps, ps2, 128, (float)NHIGH, w[18] + i * 128,
                                      w[19] + i * 128, sc, sh);
    k_gemm_lin<128, true, true, false><<<g1, 256, 0, stream>>>(
        S2, sc, sh, w[20] + i * 16384, w[21] + i * 128, S0, NHIGH, 128);
    k_gemm_lin<128, true, true, false><<<g1, 256, 0, stream>>>(
        S2, sc, sh, w[22] + i * 16384, w[23] + i * 128, S1, NHIGH, 128);
    k_gat_hh2<false><<<12500, 256, 0, stream>>>(S0, S1, w[24] + i * 128,
                                                w[25] + i * 128, rpH, colH, S2);
  }

  // ---- Stage 5: g5 ----
  k_bn_part<<<100, 256, 0, stream>>>(S2, 128, 2, ps, ps2);
  k_bn_fin<<<128, 128, 0, stream>>>(ps, ps2, 128, (float)NHIGH, w[18] + 384,
                                    w[19] + 384, sc, sh);
  k_gemm_lin<128, true, true, false><<<g2, 256, 0, stream>>>(
      S2, sc, sh, w[26], w[27], S0, NHIGH, 64);
  k_gemm_lin<128, true, true, false><<<g2, 256, 0, stream>>>(
      S2, sc, sh, w[28], w[29], S1, NHIGH, 64);
  k_gat_hh1<true><<<12500, 256, 0, stream>>>(S0, S1, w[30], w[31], rpH, colH, S2);

  // ---- Stage 6: MLP ----
  k_gemm_lin<64, false, false, true><<<g2, 256, 0, stream>>>(
      S2, sc, sh, w[32], w[33], S0, NHIGH, 64);
  k_linear<64, 32, true><<<nb((long long)NHIGH * 32), 256, 0, stream>>>(
      S0, w[34], w[35], S1, NHIGH);
  k_linear<32, 1, false><<<nb((long long)NHIGH), 256, 0, stream>>>(
      S1, w[36], w[37], (float*)d_out, NHIGH);
}

// Round 20
// 1566.594 us; speedup vs baseline: 1.0535x; 1.0535x over previous
//
#include <hip/hip_runtime.h>
#include <hip/hip_bf16.h>

#define NLOW  8000
#define NHIGH 50000
#define NL25  200000
#define ELL   32000
#define ELH   1250000
#define EHH   800000
#define LOG2E 1.4426950408889634f

__global__ void k_fill_out(float* __restrict__ o, int n, float v) {
  int i = blockIdx.x * 256 + threadIdx.x;
  if (i < n) o[i] = v;
}

// ---------------- Stage 1: fused GCN ----------------
__global__ void k_init_deg(float* __restrict__ deg) {
  int i = blockIdx.x * 256 + threadIdx.x;
  if (i < NLOW) deg[i] = 1.0f;
}
__global__ void k_gcn_deg(const int* __restrict__ ei, float* __restrict__ deg) {
  int e = blockIdx.x * 256 + threadIdx.x;
  if (e >= ELL) return;
  int d = ei[ELL + e];
  if (d >= 0 && d < NLOW) atomicAdd(&deg[d], 1.0f);
}
__global__ void k_xa_init(const float* __restrict__ x, const float* __restrict__ deg,
                          float* __restrict__ xa) {
  int i = blockIdx.x * 256 + threadIdx.x;
  if (i >= NLOW * 125) return;
  xa[i] = x[i] / deg[i / 125];
}
__global__ void k_xa_edge(const float* __restrict__ x, const int* __restrict__ ei,
                          const float* __restrict__ deg, float* __restrict__ xa) {
  int gid = blockIdx.x * 256 + threadIdx.x;
  if (gid >= ELL * 125) return;
  int e = gid / 125, k = gid - e * 125;
  int s = ei[e], d = ei[ELL + e];
  if (s < 0 || s >= NLOW || d < 0 || d >= NLOW) return;
  float nrm = rsqrtf(deg[s]) * rsqrtf(deg[d]);
  atomicAdd(&xa[d * 125 + k], nrm * x[s * 125 + k]);
}
__global__ void k_prep_M(const float* __restrict__ W, const float* __restrict__ Wl,
                         float* __restrict__ M) {
  int gid = blockIdx.x * 256 + threadIdx.x;
  if (gid >= 125 * 2500) return;
  int vk = gid / 2500, r = gid - vk * 2500, sp = r / 100, j = r - sp * 100;
  int v = vk / 25;
  float acc = 0.f;
#pragma unroll
  for (int c = 0; c < 25; c++)
    acc = fmaf(W[vk * 625 + c * 25 + sp], Wl[(v * 25 + c) * 100 + j], acc);
  M[gid] = acc;
}
__global__ void k_prep_b2(const float* __restrict__ b, const float* __restrict__ Wl,
                          const float* __restrict__ bl, float* __restrict__ b2) {
  int gid = blockIdx.x * 256 + threadIdx.x;
  if (gid >= 2500) return;
  int sp = gid / 100, j = gid - sp * 100;
  float acc = bl[j];
  for (int v = 0; v < 5; v++)
#pragma unroll
    for (int c = 0; c < 25; c++)
      acc = fmaf(b[v * 625 + c * 25 + sp], Wl[(v * 25 + c) * 100 + j], acc);
  b2[gid] = acc;
}

// Tiled GEMM -> bf16 hl100, head-pair interleaved.
__global__ void k_hlT_gemm(const float* __restrict__ A, const float* __restrict__ M,
                           const float* __restrict__ b2v,
                           unsigned short* __restrict__ out16) {
  __shared__ float As[32 * 68];
  __shared__ float Bs[32 * 68];
  int t = threadIdx.x;
  int tx = t & 15, ty = t >> 4;
  int row0 = blockIdx.x * 64, col0 = blockIdx.y * 64;
  float acc[4][4];
#pragma unroll
  for (int i = 0; i < 4; i++)
#pragma unroll
    for (int j = 0; j < 4; j++) acc[i][j] = 0.f;
  for (int k0 = 0; k0 < 125; k0 += 32) {
    int kw = 125 - k0; if (kw > 32) kw = 32;
    for (int l = t; l < 64 * 32; l += 256) {
      int r = l >> 5, kk = l & 31;
      As[kk * 68 + r] = (kk < kw) ? A[(size_t)(row0 + r) * 125 + k0 + kk] : 0.f;
    }
    for (int l = t; l < 32 * 64; l += 256) {
      int kk = l >> 6, bb = l & 63;
      int b = col0 + bb;
      float v = 0.f;
      if (kk < kw && b < 2500) {
        int sp = b / 100, r = b - sp * 100;
        int g = r / 50, q = r - g * 50, cc = q >> 1, hp = q & 1;
        int cm = sp * 100 + (2 * g + hp) * 25 + cc;
        v = M[(size_t)(k0 + kk) * 2500 + cm];
      }
      Bs[kk * 68 + bb] = v;
    }
    __syncthreads();
#pragma unroll 8
    for (int kk = 0; kk < 32; kk++) {
      float4 a4 = *(const float4*)&As[kk * 68 + ty * 4];
      float4 b4 = *(const float4*)&Bs[kk * 68 + tx * 4];
      float a[4] = {a4.x, a4.y, a4.z, a4.w};
      float b[4] = {b4.x, b4.y, b4.z, b4.w};
#pragma unroll
      for (int i = 0; i < 4; i++)
#pragma unroll
        for (int j = 0; j < 4; j++) acc[i][j] = fmaf(a[i], b[j], acc[i][j]);
    }
    __syncthreads();
  }
#pragma unroll
  for (int i = 0; i < 4; i++) {
    int r = row0 + ty * 4 + i;
#pragma unroll
    for (int j = 0; j < 4; j++) {
      int b = col0 + tx * 4 + j;
      if (b < 2500) {
        int sp = b / 100, rr = b - sp * 100;
        int g = rr / 50, q = rr - g * 50, cc = q >> 1, hp = q & 1;
        int cm = sp * 100 + (2 * g + hp) * 25 + cc;
        __hip_bfloat16 hv = __float2bfloat16(acc[i][j] + b2v[cm]);
        out16[(size_t)r * 2500 + b] = *(unsigned short*)&hv;
      }
    }
  }
}

// ---- Generic 64x64-tile GEMM, fused BN(+ReLU) on input, ReLU on out ----
template <int CIN, bool BN, bool INRELU, bool OUTRELU>
__global__ void k_gemm_lin(const float* __restrict__ X, const float* __restrict__ sc,
                           const float* __restrict__ sh, const float* __restrict__ W,
                           const float* __restrict__ bias, float* __restrict__ out,
                           int n, int COUT) {
  __shared__ float As[32 * 68];
  __shared__ float Bs[32 * 68];
  int t = threadIdx.x;
  int tx = t & 15, ty = t >> 4;
  int row0 = blockIdx.x * 64, col0 = blockIdx.y * 64;
  float acc[4][4];
#pragma unroll
  for (int i = 0; i < 4; i++)
#pragma unroll
    for (int j = 0; j < 4; j++) acc[i][j] = 0.f;
  for (int k0 = 0; k0 < CIN; k0 += 32) {
    int kw = CIN - k0; if (kw > 32) kw = 32;
    for (int l = t; l < 64 * 32; l += 256) {
      int r = l >> 5, kk = l & 31;
      float v = 0.f;
      int rr = row0 + r;
      if (kk < kw && rr < n) {
        int k = k0 + kk;
        v = X[(size_t)rr * CIN + k];
        if (BN) v = fmaf(v, sc[k], sh[k]);
        if (INRELU) v = fmaxf(v, 0.f);
      }
      As[kk * 68 + r] = v;
    }
    for (int l = t; l < 32 * 64; l += 256) {
      int kk = l >> 6, cc = l & 63;
      Bs[kk * 68 + cc] = (kk < kw) ? W[(size_t)(k0 + kk) * COUT + col0 + cc] : 0.f;
    }
    __syncthreads();
#pragma unroll 8
    for (int kk = 0; kk < 32; kk++) {
      float4 a4 = *(const float4*)&As[kk * 68 + ty * 4];
      float4 b4 = *(const float4*)&Bs[kk * 68 + tx * 4];
      float a[4] = {a4.x, a4.y, a4.z, a4.w};
      float b[4] = {b4.x, b4.y, b4.z, b4.w};
#pragma unroll
      for (int i = 0; i < 4; i++)
#pragma unroll
        for (int j = 0; j < 4; j++) acc[i][j] = fmaf(a[i], b[j], acc[i][j]);
    }
    __syncthreads();
  }
#pragma unroll
  for (int i = 0; i < 4; i++) {
    int r = row0 + ty * 4 + i;
    if (r >= n) continue;
#pragma unroll
    for (int j = 0; j < 4; j++) {
      int c = col0 + tx * 4 + j;
      float v = acc[i][j] + bias[c];
      if (OUTRELU) v = fmaxf(v, 0.f);
      out[(size_t)r * COUT + c] = v;
    }
  }
}

// ---------------- CSR build ----------------
__global__ void k_hist(const int* __restrict__ dst, int E, int* __restrict__ cnt) {
  int e = blockIdx.x * 256 + threadIdx.x;
  if (e >= E) return;
  int d = dst[e];
  if (d >= 0 && d < NHIGH) atomicAdd(&cnt[d], 1);
}
__global__ void k_scan1(const int* __restrict__ cnt, int* __restrict__ rp,
                        int* __restrict__ part, int N) {
  __shared__ int sh[256];
  int i = blockIdx.x * 256 + threadIdx.x;
  int v = (i < N) ? cnt[i] : 0;
  sh[threadIdx.x] = v;
  __syncthreads();
  for (int off = 1; off < 256; off <<= 1) {
    int t = (threadIdx.x >= off) ? sh[threadIdx.x - off] : 0;
    __syncthreads();
    sh[threadIdx.x] += t;
    __syncthreads();
  }
  if (i < N) rp[i] = sh[threadIdx.x] - v;
  if (threadIdx.x == 255) part[blockIdx.x] = sh[255];
}
__global__ void k_scan2(int* __restrict__ part, int nb) {
  __shared__ int sh[256];
  int v = (threadIdx.x < nb) ? part[threadIdx.x] : 0;
  sh[threadIdx.x] = v;
  __syncthreads();
  for (int off = 1; off < 256; off <<= 1) {
    int t = (threadIdx.x >= off) ? sh[threadIdx.x - off] : 0;
    __syncthreads();
    sh[threadIdx.x] += t;
    __syncthreads();
  }
  if (threadIdx.x < nb) part[threadIdx.x] = sh[threadIdx.x] - v;
}
__global__ void k_scan3(int* __restrict__ rp, const int* __restrict__ part, int N, int E) {
  int i = blockIdx.x * 256 + threadIdx.x;
  if (i < N) rp[i] += part[i / 256];
  if (i == 0) rp[N] = E;
}
__global__ void k_csr_scatter(const int* __restrict__ src, const int* __restrict__ dst,
                              const int* __restrict__ rp, int* __restrict__ fil,
                              int* __restrict__ col, int E) {
  int e = blockIdx.x * 256 + threadIdx.x;
  if (e >= E) return;
  int d = dst[e];
  if (d < 0 || d >= NHIGH) return;
  int pos = rp[d] + atomicAdd(&fil[d], 1);
  if (pos >= 0 && pos < E) col[pos] = src[e];
}

// ---------------- Stage 2: bipartite GATv2, fused, no-max softmax, 2-edge unroll ----------------
__global__ void k_gat_th(const unsigned* __restrict__ hlu, const float* __restrict__ z,
                         const float* __restrict__ wr, const float* __restrict__ br,
                         const float* __restrict__ att, const int* __restrict__ rp,
                         const int* __restrict__ col, float* __restrict__ acc25) {
  int d = blockIdx.x, lane = threadIdx.x;
  int beg = rp[d];
  int deg = rp[d + 1] - beg;
  if (beg < 0) beg = 0;
  if (deg < 0) deg = 0;
  if (beg + deg > ELH) deg = (ELH - beg > 0) ? (ELH - beg) : 0;
  float zd = z[d];
  int g = lane >> 5, cc = lane & 31;
  bool act = cc < 25;
  int j0 = 50 * g + (act ? cc : 0), j1 = j0 + 25;
  float hrv0 = 0.f, atv0 = 0.f, hrv1 = 0.f, atv1 = 0.f;
  if (act) {
    hrv0 = fmaf(zd, wr[j0], br[j0]); atv0 = att[j0] * LOG2E;
    hrv1 = fmaf(zd, wr[j1], br[j1]); atv1 = att[j1] * LOG2E;
  }
  bool hi = (lane & 16) != 0;
  float den0 = 0.f, a0 = 0.f, den1 = 0.f, a1 = 0.f;
  int i = 0;
  for (; i + 2 <= deg; i += 2) {
    int sA = col[beg + i];
    int sB = col[beg + i + 1];
    if (sA < 0 || sA >= NL25) sA = 0;
    if (sB < 0 || sB >= NL25) sB = 0;
    unsigned uA = act ? hlu[(size_t)sA * 50 + g * 25 + cc] : 0u;
    unsigned uB = act ? hlu[(size_t)sB * 50 + g * 25 + cc] : 0u;
    float r0a = __uint_as_float(uA << 16), r1a = __uint_as_float(uA & 0xffff0000u);
    float r0b = __uint_as_float(uB << 16), r1b = __uint_as_float(uB & 0xffff0000u);
    float e0a = r0a + hrv0; e0a = (e0a > 0.f) ? e0a : 0.2f * e0a;
    float e1a = r1a + hrv1; e1a = (e1a > 0.f) ? e1a : 0.2f * e1a;
    float e0b = r0b + hrv0; e0b = (e0b > 0.f) ? e0b : 0.2f * e0b;
    float e1b = r1b + hrv1; e1b = (e1b > 0.f) ? e1b : 0.2f * e1b;
    float p0a = e0a * atv0, p1a = e1a * atv1;
    float p0b = e0b * atv0, p1b = e1b * atv1;
    float qa = (hi ? p1a : p0a) + __shfl_xor(hi ? p0a : p1a, 16, 64);
    float qb = (hi ? p1b : p0b) + __shfl_xor(hi ? p0b : p1b, 16, 64);
#pragma unroll
    for (int off = 8; off > 0; off >>= 1) {
      qa += __shfl_xor(qa, off, 64);
      qb += __shfl_xor(qb, off, 64);
    }
    float oa = __shfl_xor(qa, 16, 64);
    float ob = __shfl_xor(qb, 16, 64);
    p0a = hi ? oa : qa; p1a = hi ? qa : oa;
    p0b = hi ? ob : qb; p1b = hi ? qb : ob;
    float w0a = exp2f(p0a), w1a = exp2f(p1a);
    float w0b = exp2f(p0b), w1b = exp2f(p1b);
    den0 += w0a + w0b;
    den1 += w1a + w1b;
    a0 = fmaf(w0a, r0a, a0); a0 = fmaf(w0b, r0b, a0);
    a1 = fmaf(w1a, r1a, a1); a1 = fmaf(w1b, r1b, a1);
  }
  if (i < deg) {
    int s = col[beg + i];
    if (s < 0 || s >= NL25) s = 0;
    unsigned u = act ? hlu[(size_t)s * 50 + g * 25 + cc] : 0u;
    float r0 = __uint_as_float(u << 16);
    float r1 = __uint_as_float(u & 0xffff0000u);
    float e0 = r0 + hrv0; e0 = (e0 > 0.f) ? e0 : 0.2f * e0;
    float e1 = r1 + hrv1; e1 = (e1 > 0.f) ? e1 : 0.2f * e1;
    float p0 = e0 * atv0, p1 = e1 * atv1;
    float q = (hi ? p1 : p0) + __shfl_xor(hi ? p0 : p1, 16, 64);
#pragma unroll
    for (int off = 8; off > 0; off >>= 1) q += __shfl_xor(q, off, 64);
    float o = __shfl_xor(q, 16, 64);
    p0 = hi ? o : q;
    p1 = hi ? q : o;
    float w0 = exp2f(p0), w1 = exp2f(p1);
    den0 += w0; a0 = fmaf(w0, r0, a0);
    den1 += w1; a1 = fmaf(w1, r1, a1);
  }
  float v = a0 / fmaxf(den0, 1e-30f) + a1 / fmaxf(den1, 1e-30f);
  float other = __shfl_down(v, 32, 64);
  if (lane < 25) acc25[d * 25 + lane] = v + other;
}
__global__ void k_th_fin(const float* __restrict__ acc25, const int* __restrict__ rp,
                         const float* __restrict__ bias, const float* __restrict__ z,
                         float* __restrict__ x26) {
  int gid = blockIdx.x * 256 + threadIdx.x;
  int node = gid / 26, j = gid - node * 26;
  if (node >= NHIGH) return;
  if (j == 0) {
    x26[node * 26] = z[node];
  } else {
    int dg = rp[node + 1] - rp[node];
    if (dg < 1) dg = 1;
    x26[node * 26 + j] = acc25[node * 25 + j - 1] / (4.0f * (float)dg) + bias[j - 1];
  }
}

// ---------------- high-res GATv2: no-max softmax, 2-edge unroll, float2 channels ----------------
template <bool RELU>
__global__ void k_gat_hh2(const float* __restrict__ hl, const float* __restrict__ hr,
                          const float* __restrict__ att, const float* __restrict__ bias,
                          const int* __restrict__ rp, const int* __restrict__ col,
                          float* __restrict__ out) {
  const int F = 128;
  int d = blockIdx.x, lane = threadIdx.x;
  int h = lane >> 5, l2 = lane & 31;
  int c0 = h * 64 + 2 * l2;
  int beg = rp[d];
  int deg = rp[d + 1] - beg;
  if (beg < 0) beg = 0;
  if (deg < 0) deg = 0;
  if (beg + deg > EHH) deg = (EHH - beg > 0) ? (EHH - beg) : 0;
  int tot = deg + 1;  // + self loop
  float2 hrv = *(const float2*)&hr[(size_t)d * F + c0];
  float2 atv = *(const float2*)&att[c0];
  atv.x *= LOG2E; atv.y *= LOG2E;
  bool hi = (lane & 16) != 0;
  float den = 0.f, acc0 = 0.f, acc1 = 0.f;
  int i = 0;
  for (; i + 2 <= tot; i += 2) {
    int sA = (i < deg) ? col[beg + i] : d;
    int sB = (i + 1 < deg) ? col[beg + i + 1] : d;
    if (sA < 0 || sA >= NHIGH) sA = 0;
    if (sB < 0 || sB >= NHIGH) sB = 0;
    float2 ra = *(const float2*)&hl[(size_t)sA * F + c0];
    float2 rb = *(const float2*)&hl[(size_t)sB * F + c0];
    float e0a = ra.x + hrv.x; e0a = (e0a > 0.f) ? e0a : 0.2f * e0a;
    float e1a = ra.y + hrv.y; e1a = (e1a > 0.f) ? e1a : 0.2f * e1a;
    float pA = fmaf(e0a, atv.x, e1a * atv.y);
    float e0b = rb.x + hrv.x; e0b = (e0b > 0.f) ? e0b : 0.2f * e0b;
    float e1b = rb.y + hrv.y; e1b = (e1b > 0.f) ? e1b : 0.2f * e1b;
    float pB = fmaf(e0b, atv.x, e1b * atv.y);
    float own = hi ? pB : pA;
    float oth = hi ? pA : pB;
    float q = own + __shfl_xor(oth, 16, 64);
#pragma unroll
    for (int off = 8; off > 0; off >>= 1) q += __shfl_xor(q, off, 64);
    float o = __shfl_xor(q, 16, 64);
    pA = hi ? o : q;
    pB = hi ? q : o;
    float wA = exp2f(pA), wB = exp2f(pB);
    den += wA + wB;
    acc0 = fmaf(wA, ra.x, acc0); acc0 = fmaf(wB, rb.x, acc0);
    acc1 = fmaf(wA, ra.y, acc1); acc1 = fmaf(wB, rb.y, acc1);
  }
  if (i < tot) {
    int s = (i < deg) ? col[beg + i] : d;
    if (s < 0 || s >= NHIGH) s = 0;
    float2 r = *(const float2*)&hl[(size_t)s * F + c0];
    float e0 = r.x + hrv.x; e0 = (e0 > 0.f) ? e0 : 0.2f * e0;
    float e1 = r.y + hrv.y; e1 = (e1 > 0.f) ? e1 : 0.2f * e1;
    float p = fmaf(e0, atv.x, e1 * atv.y);
#pragma unroll
    for (int off = 16; off > 0; off >>= 1) p += __shfl_xor(p, off, 64);
    float w_ = exp2f(p);
    den += w_;
    acc0 = fmaf(w_, r.x, acc0);
    acc1 = fmaf(w_, r.y, acc1);
  }
  float inv = 1.0f / (fmaxf(den, 1e-30f) * (float)tot);
  float2 bv = *(const float2*)&bias[c0];
  float v0 = acc0 * inv + bv.x;
  float v1 = acc1 * inv + bv.y;
  if (RELU) { v0 = fmaxf(v0, 0.f); v1 = fmaxf(v1, 0.f); }
  *(float2*)&out[(size_t)d * F + c0] = make_float2(v0, v1);
}
template <bool RELU>
__global__ void k_gat_hh1(const float* __restrict__ hl, const float* __restrict__ hr,
                          const float* __restrict__ att, const float* __restrict__ bias,
                          const int* __restrict__ rp, const int* __restrict__ col,
                          float* __restrict__ out) {
  const int F = 64;
  int d = blockIdx.x, lane = threadIdx.x;
  int beg = rp[d];
  int deg = rp[d + 1] - beg;
  if (beg < 0) beg = 0;
  if (deg < 0) deg = 0;
  if (beg + deg > EHH) deg = (EHH - beg > 0) ? (EHH - beg) : 0;
  int tot = deg + 1;
  float hrv = hr[(size_t)d * F + lane];
  float atv = att[lane] * LOG2E;
  bool hi = lane >= 32;
  float den = 0.f, acc = 0.f;
  int i = 0;
  for (; i + 2 <= tot; i += 2) {
    int sA = (i < deg) ? col[beg + i] : d;
    int sB = (i + 1 < deg) ? col[beg + i + 1] : d;
    if (sA < 0 || sA >= NHIGH) sA = 0;
    if (sB < 0 || sB >= NHIGH) sB = 0;
    float rA = hl[(size_t)sA * F + lane];
    float rB = hl[(size_t)sB * F + lane];
    float eA = rA + hrv; eA = (eA > 0.f) ? eA : 0.2f * eA;
    float eB = rB + hrv; eB = (eB > 0.f) ? eB : 0.2f * eB;
    float pA = eA * atv, pB = eB * atv;
    float own = hi ? pB : pA;
    float oth = hi ? pA : pB;
    float q = own + __shfl_xor(oth, 32, 64);
#pragma unroll
    for (int off = 16; off > 0; off >>= 1) q += __shfl_xor(q, off, 64);
    float o = __shfl_xor(q, 32, 64);
    pA = hi ? o : q;
    pB = hi ? q : o;
    float wA = exp2f(pA), wB = exp2f(pB);
    den += wA + wB;
    acc = fmaf(wA, rA, acc);
    acc = fmaf(wB, rB, acc);
  }
  if (i < tot) {
    int s = (i < deg) ? col[beg + i] : d;
    if (s < 0 || s >= NHIGH) s = 0;
    float r = hl[(size_t)s * F + lane];
    float e = r + hrv; e = (e > 0.f) ? e : 0.2f * e;
    float p = e * atv;
#pragma unroll
    for (int off = 32; off > 0; off >>= 1) p += __shfl_xor(p, off, 64);
    float w_ = exp2f(p);
    den += w_;
    acc = fmaf(w_, r, acc);
  }
  float v = acc / (fmaxf(den, 1e-30f) * (float)tot) + bias[lane];
  if (RELU) v = fmaxf(v, 0.f);
  out[(size_t)d * F + lane] = v;
}

// ---------------- BatchNorm: parallel partials + f64 finalize -> scale/shift ----------------
__global__ void k_bn_part(const float* __restrict__ x, int C, int tpc,
                          float* __restrict__ ps, float* __restrict__ ps2) {
  int gch = blockIdx.x, t = threadIdx.x;
  int c = t % C, sub = t / C;
  float s = 0.f, s2 = 0.f;
  if (sub < tpc) {
    for (int r = gch * 500 + sub; r < gch * 500 + 500; r += tpc) {
      float v = x[(size_t)r * C + c];
      s += v;
      s2 = fmaf(v, v, s2);
    }
  }
  __shared__ float ls[256], ls2[256];
  ls[t] = s; ls2[t] = s2;
  __syncthreads();
  if (t < C) {
    float a = 0.f, a2 = 0.f;
    for (int u = 0; u < tpc; u++) { a += ls[u * C + t]; a2 += ls2[u * C + t]; }
    ps[gch * C + t] = a;
    ps2[gch * C + t] = a2;
  }
}
__global__ void k_bn_fin(const float* __restrict__ ps, const float* __restrict__ ps2,
                         int C, float n, const float* __restrict__ g,
                         const float* __restrict__ b, float* __restrict__ sc,
                         float* __restrict__ sh) {
  int c = blockIdx.x, t = threadIdx.x;
  __shared__ double ds[128], ds2[128];
  double a = 0, a2 = 0;
  for (int q = t; q < 100; q += 128) { a += ps[q * C + c]; a2 += ps2[q * C + c]; }
  ds[t] = a; ds2[t] = a2;
  __syncthreads();
  for (int off = 64; off > 0; off >>= 1) {
    if (t < off) { ds[t] += ds[t + off]; ds2[t] += ds2[t + off]; }
    __syncthreads();
  }
  if (t == 0) {
    double m = ds[0] / n;
    double v = ds2[0] / n - m * m;
    if (v < 0) v = 0;
    float scale = g[c] * rsqrtf((float)v + 1e-5f);
    sc[c] = scale;
    sh[c] = b[c] - (float)m * scale;
  }
}

// small naive linear for MLP tails
template <int CIN, int COUT, bool RELU>
__global__ void k_linear(const float* __restrict__ x, const float* __restrict__ W,
                         const float* __restrict__ b, float* __restrict__ y, int n) {
  long long gid = (long long)blockIdx.x * 256 + threadIdx.x;
  int node = (int)(gid / COUT);
  int j = (int)(gid - (long long)node * COUT);
  if (node >= n) return;
  const float* xr = x + (size_t)node * CIN;
  float acc = b[j];
#pragma unroll 4
  for (int k = 0; k < CIN; k++) acc = fmaf(xr[k], W[k * COUT + j], acc);
  if (RELU) acc = fmaxf(acc, 0.f);
  y[(size_t)node * COUT + j] = acc;
}

extern "C" void kernel_launch(void* const* d_in, const int* in_sizes, int n_in,
                              void* d_out, int out_size, void* d_ws, size_t ws_size,
                              hipStream_t stream) {
  auto nb = [](long long t) { return dim3((unsigned)((t + 255) / 256)); };
  static const int FSZ[38] = {
      1000000, 50000, 78125, 3125, 12500, 100, 100, 100, 100, 25, 26, 26,
      3328, 128, 3328, 128, 128, 128, 512, 512, 49152, 384, 49152, 384, 384,
      384, 8192, 64, 8192, 64, 64, 64, 4096, 64, 2048, 32, 32, 1};
  static const int ISZ[4] = {64000, 1250000, 1250000, 1600000};
  if (n_in != 42) {
    k_fill_out<<<nb(out_size), 256, 0, stream>>>((float*)d_out, out_size, 500000.0f);
    return;
  }
  bool szok = true;
  for (int i = 0; i < 38; i++) szok &= (in_sizes[i] == FSZ[i]);
  for (int i = 0; i < 4; i++) szok &= (in_sizes[38 + i] == ISZ[i]);
  if (!szok) {
    k_fill_out<<<nb(out_size), 256, 0, stream>>>((float*)d_out, out_size, 600000.0f);
    return;
  }
  const size_t REQUIRED = 20146000ull * 4ull;
  if (ws_size < REQUIRED) {
    hipMemsetAsync(d_out, 0, (size_t)out_size * 4, stream);
    return;
  }

  const float* w[38];
  for (int i = 0; i < 38; i++) w[i] = (const float*)d_in[i];  // f32 (verified r6/r9)
  const int* ei_ll = (const int*)d_in[38];  // int32 (verified r9/r10)
  const int* s_l2h = (const int*)d_in[39];
  const int* d_l2h = (const int*)d_in[40];
  const int* ei_hh = (const int*)d_in[41];

  float* ws = (float*)d_ws;
  float* S0 = ws;                       // [0, 6.4M)
  float* S1 = ws + 6400000;             // [6.4M, 12.8M)
  float* S2 = ws + 12800000;            // [12.8M, 19.2M)
  unsigned short* hl100 = (unsigned short*)ws;  // [20M bf16] = 10M words
  float* acc25 = ws + 10000000;         // [1,250,000]
  int*  rpT  = (int*)(ws + 11300000);   // [50,001]
  int*  filT = (int*)(ws + 11360000);   // [50,000]
  int*  colT = (int*)(ws + 11450000);   // [1,250,000] -> 12.7M
  float* xa  = ws + 12800000;           // [1,000,000]
  float* Mt  = ws + 13800000;           // [312,500]
  float* b2  = ws + 14112500;           // [2,500]
  float* x26 = ws + 14200000;           // [1,300,000] (dead before S2 written)
  int*  rpH  = (int*)(ws + 19200000);   // [50,001]
  int*  filH = (int*)(ws + 19260000);   // [50,000]
  int*  colH = (int*)(ws + 19310000);   // [800,000] -> 20,110,000
  float* deg = ws + 20110000;           // [8,000]
  float* sc  = ws + 20118000;           // [128]
  float* sh  = ws + 20118128;           // [128]
  int*  part = (int*)(ws + 20118256);   // [512]
  float* ps   = ws + 20120000;          // [12,800]
  float* ps2  = ws + 20132800;          // [12,800] -> 20,145,600

  // ---- CSR for both graphs ----
  auto build_csr = [&](const int* src, const int* dst, int E, int* rp, int* fil,
                       int* col) {
    hipMemsetAsync(fil, 0, NHIGH * 4, stream);
    k_hist<<<nb(E), 256, 0, stream>>>(dst, E, fil);
    int nblk = (NHIGH + 255) / 256;
    k_scan1<<<nblk, 256, 0, stream>>>(fil, rp, part, NHIGH);
    k_scan2<<<1, 256, 0, stream>>>(part, nblk);
    k_scan3<<<nb(NHIGH), 256, 0, stream>>>(rp, part, NHIGH, E);
    hipMemsetAsync(fil, 0, NHIGH * 4, stream);
    k_csr_scatter<<<nb(E), 256, 0, stream>>>(src, dst, rp, fil, col, E);
  };
  build_csr(s_l2h, d_l2h, ELH, rpT, filT, colT);
  build_csr(ei_hh, ei_hh + EHH, EHH, rpH, filH, colH);

  // ---- Stage 1: GCN fold ----
  k_init_deg<<<nb(NLOW), 256, 0, stream>>>(deg);
  k_gcn_deg<<<nb(ELL), 256, 0, stream>>>(ei_ll, deg);
  k_xa_init<<<nb(NLOW * 125), 256, 0, stream>>>(w[0], deg, xa);
  k_xa_edge<<<nb((long long)ELL * 125), 256, 0, stream>>>(w[0], ei_ll, deg, xa);
  k_prep_M<<<nb(125 * 2500), 256, 0, stream>>>(w[2], w[4], Mt);
  k_prep_b2<<<nb(2500), 256, 0, stream>>>(w[3], w[4], w[5], b2);

  // ---- Stage 2: th GATv2, single fused pass ----
  k_hlT_gemm<<<dim3(125, 40), 256, 0, stream>>>(xa, Mt, b2, hl100);
  k_gat_th<<<NHIGH, 64, 0, stream>>>((const unsigned*)hl100, w[1], w[6], w[7], w[8],
                                     rpT, colT, acc25);
  k_th_fin<<<nb((long long)NHIGH * 26), 256, 0, stream>>>(acc25, rpT, w[9], w[1], x26);

  const dim3 g1(782, 2), g2(782, 1);

  // ---- Stage 3: bn0 + g1 ----
  k_bn_part<<<100, 256, 0, stream>>>(x26, 26, 9, ps, ps2);
  k_bn_fin<<<26, 128, 0, stream>>>(ps, ps2, 26, (float)NHIGH, w[10], w[11], sc, sh);
  k_gemm_lin<26, true, false, false><<<g1, 256, 0, stream>>>(
      x26, sc, sh, w[12], w[13], S0, NHIGH, 128);
  k_gemm_lin<26, true, false, false><<<g1, 256, 0, stream>>>(
      x26, sc, sh, w[14], w[15], S1, NHIGH, 128);
  k_gat_hh2<false><<<NHIGH, 64, 0, stream>>>(S0, S1, w[16], w[17], rpH, colH, S2);

  // ---- Stage 4: 3x gm ----
  for (int i = 0; i < 3; i++) {
    k_bn_part<<<100, 256, 0, stream>>>(S2, 128, 2, ps, ps2);
    k_bn_fin<<<128, 128, 0, stream>>>(ps, ps2, 128, (float)NHIGH, w[18] + i * 128,
                                      w[19] + i * 128, sc, sh);
    k_gemm_lin<128, true, true, false><<<g1, 256, 0, stream>>>(
        S2, sc, sh, w[20] + i * 16384, w[21] + i * 128, S0, NHIGH, 128);
    k_gemm_lin<128, true, true, false><<<g1, 256, 0, stream>>>(
        S2, sc, sh, w[22] + i * 16384, w[23] + i * 128, S1, NHIGH, 128);
    k_gat_hh2<false><<<NHIGH, 64, 0, stream>>>(S0, S1, w[24] + i * 128,
                                               w[25] + i * 128, rpH, colH, S2);
  }

  // ---- Stage 5: g5 ----
  k_bn_part<<<100, 256, 0, stream>>>(S2, 128, 2, ps, ps2);
  k_bn_fin<<<128, 128, 0, stream>>>(ps, ps2, 128, (float)NHIGH, w[18] + 384,
                                    w[19] + 384, sc, sh);
  k_gemm_lin<128, true, true, false><<<g2, 256, 0, stream>>>(
      S2, sc, sh, w[26], w[27], S0, NHIGH, 64);
  k_gemm_lin<128, true, true, false><<<g2, 256, 0, stream>>>(
      S2, sc, sh, w[28], w[29], S1, NHIGH, 64);
  k_gat_hh1<true><<<NHIGH, 64, 0, stream>>>(S0, S1, w[30], w[31], rpH, colH, S2);

  // ---- Stage 6: MLP ----
  k_gemm_lin<64, false, false, true><<<g2, 256, 0, stream>>>(
      S2, sc, sh, w[32], w[33], S0, NHIGH, 64);
  k_linear<64, 32, true><<<nb((long long)NHIGH * 32), 256, 0, stream>>>(
      S0, w[34], w[35], S1, NHIGH);
  k_linear<32, 1, false><<<nb((long long)NHIGH), 256, 0, stream>>>(
      S1, w[36], w[37], (float*)d_out, NHIGH);
}

// Round 21
// 1545.259 us; speedup vs baseline: 1.0680x; 1.0138x over previous
//
#include <hip/hip_runtime.h>
#include <hip/hip_bf16.h>

#define NLOW  8000
#define NHIGH 50000
#define NL25  200000
#define ELL   32000
#define ELH   1250000
#define EHH   800000
#define LOG2E 1.4426950408889634f

__global__ void k_fill_out(float* __restrict__ o, int n, float v) {
  int i = blockIdx.x * 256 + threadIdx.x;
  if (i < n) o[i] = v;
}

// ---------------- Stage 1: fused GCN ----------------
__global__ void k_init_deg(float* __restrict__ deg) {
  int i = blockIdx.x * 256 + threadIdx.x;
  if (i < NLOW) deg[i] = 1.0f;
}
__global__ void k_gcn_deg(const int* __restrict__ ei, float* __restrict__ deg) {
  int e = blockIdx.x * 256 + threadIdx.x;
  if (e >= ELL) return;
  int d = ei[ELL + e];
  if (d >= 0 && d < NLOW) atomicAdd(&deg[d], 1.0f);
}
__global__ void k_xa_init(const float* __restrict__ x, const float* __restrict__ deg,
                          float* __restrict__ xa) {
  int i = blockIdx.x * 256 + threadIdx.x;
  if (i >= NLOW * 125) return;
  xa[i] = x[i] / deg[i / 125];
}
__global__ void k_xa_edge(const float* __restrict__ x, const int* __restrict__ ei,
                          const float* __restrict__ deg, float* __restrict__ xa) {
  int gid = blockIdx.x * 256 + threadIdx.x;
  if (gid >= ELL * 125) return;
  int e = gid / 125, k = gid - e * 125;
  int s = ei[e], d = ei[ELL + e];
  if (s < 0 || s >= NLOW || d < 0 || d >= NLOW) return;
  float nrm = rsqrtf(deg[s]) * rsqrtf(deg[d]);
  atomicAdd(&xa[d * 125 + k], nrm * x[s * 125 + k]);
}
// M pre-permuted to head-pair-interleaved layout: column b = sp*100 + g*50 + 2*cc + hp
// for source col sp*100 + (2g+hp)*25 + cc.  (permutation folded here, once)
__global__ void k_prep_M(const float* __restrict__ W, const float* __restrict__ Wl,
                         float* __restrict__ M) {
  int gid = blockIdx.x * 256 + threadIdx.x;
  if (gid >= 125 * 2500) return;
  int vk = gid / 2500, r = gid - vk * 2500, sp = r / 100, j = r - sp * 100;
  int v = vk / 25;
  float acc = 0.f;
#pragma unroll
  for (int c = 0; c < 25; c++)
    acc = fmaf(W[vk * 625 + c * 25 + sp], Wl[(v * 25 + c) * 100 + j], acc);
  int h = j / 25, cc = j - h * 25;
  int b = sp * 100 + (h >> 1) * 50 + 2 * cc + (h & 1);
  M[(size_t)vk * 2500 + b] = acc;
}
__global__ void k_prep_b2(const float* __restrict__ b, const float* __restrict__ Wl,
                          const float* __restrict__ bl, float* __restrict__ b2) {
  int gid = blockIdx.x * 256 + threadIdx.x;
  if (gid >= 2500) return;
  int sp = gid / 100, j = gid - sp * 100;
  float acc = bl[j];
  for (int v = 0; v < 5; v++)
#pragma unroll
    for (int c = 0; c < 25; c++)
      acc = fmaf(b[v * 625 + c * 25 + sp], Wl[(v * 25 + c) * 100 + j], acc);
  int h = j / 25, cc = j - h * 25;
  int bb = sp * 100 + (h >> 1) * 50 + 2 * cc + (h & 1);
  b2[bb] = acc;
}

// Tiled GEMM -> bf16 hl100 (M/b2 already permuted; pure coalesced staging/epilogue)
__global__ void k_hlT_gemm(const float* __restrict__ A, const float* __restrict__ M,
                           const float* __restrict__ b2v,
                           unsigned short* __restrict__ out16) {
  __shared__ float As[32 * 68];
  __shared__ float Bs[32 * 68];
  int t = threadIdx.x;
  int tx = t & 15, ty = t >> 4;
  int row0 = blockIdx.x * 64, col0 = blockIdx.y * 64;
  float acc[4][4];
#pragma unroll
  for (int i = 0; i < 4; i++)
#pragma unroll
    for (int j = 0; j < 4; j++) acc[i][j] = 0.f;
  for (int k0 = 0; k0 < 125; k0 += 32) {
    int kw = 125 - k0; if (kw > 32) kw = 32;
    for (int l = t; l < 64 * 32; l += 256) {
      int r = l >> 5, kk = l & 31;
      As[kk * 68 + r] = (kk < kw) ? A[(size_t)(row0 + r) * 125 + k0 + kk] : 0.f;
    }
    for (int l = t; l < 32 * 64; l += 256) {
      int kk = l >> 6, bb = l & 63;
      int b = col0 + bb;
      Bs[kk * 68 + bb] =
          (kk < kw && b < 2500) ? M[(size_t)(k0 + kk) * 2500 + b] : 0.f;
    }
    __syncthreads();
#pragma unroll 8
    for (int kk = 0; kk < 32; kk++) {
      float4 a4 = *(const float4*)&As[kk * 68 + ty * 4];
      float4 b4 = *(const float4*)&Bs[kk * 68 + tx * 4];
      float a[4] = {a4.x, a4.y, a4.z, a4.w};
      float b[4] = {b4.x, b4.y, b4.z, b4.w};
#pragma unroll
      for (int i = 0; i < 4; i++)
#pragma unroll
        for (int j = 0; j < 4; j++) acc[i][j] = fmaf(a[i], b[j], acc[i][j]);
    }
    __syncthreads();
  }
#pragma unroll
  for (int i = 0; i < 4; i++) {
    int r = row0 + ty * 4 + i;
#pragma unroll
    for (int j = 0; j < 4; j++) {
      int b = col0 + tx * 4 + j;
      if (b < 2500) {
        __hip_bfloat16 hv = __float2bfloat16(acc[i][j] + b2v[b]);
        out16[(size_t)r * 2500 + b] = *(unsigned short*)&hv;
      }
    }
  }
}

// ---- Generic 64x64-tile GEMM, fused BN(+ReLU) on input, ReLU on out ----
template <int CIN, bool BN, bool INRELU, bool OUTRELU>
__global__ void k_gemm_lin(const float* __restrict__ X, const float* __restrict__ sc,
                           const float* __restrict__ sh, const float* __restrict__ W,
                           const float* __restrict__ bias, float* __restrict__ out,
                           int n, int COUT) {
  __shared__ float As[32 * 68];
  __shared__ float Bs[32 * 68];
  int t = threadIdx.x;
  int tx = t & 15, ty = t >> 4;
  int row0 = blockIdx.x * 64, col0 = blockIdx.y * 64;
  float acc[4][4];
#pragma unroll
  for (int i = 0; i < 4; i++)
#pragma unroll
    for (int j = 0; j < 4; j++) acc[i][j] = 0.f;
  for (int k0 = 0; k0 < CIN; k0 += 32) {
    int kw = CIN - k0; if (kw > 32) kw = 32;
    for (int l = t; l < 64 * 32; l += 256) {
      int r = l >> 5, kk = l & 31;
      float v = 0.f;
      int rr = row0 + r;
      if (kk < kw && rr < n) {
        int k = k0 + kk;
        v = X[(size_t)rr * CIN + k];
        if (BN) v = fmaf(v, sc[k], sh[k]);
        if (INRELU) v = fmaxf(v, 0.f);
      }
      As[kk * 68 + r] = v;
    }
    for (int l = t; l < 32 * 64; l += 256) {
      int kk = l >> 6, cc = l & 63;
      Bs[kk * 68 + cc] = (kk < kw) ? W[(size_t)(k0 + kk) * COUT + col0 + cc] : 0.f;
    }
    __syncthreads();
#pragma unroll 8
    for (int kk = 0; kk < 32; kk++) {
      float4 a4 = *(const float4*)&As[kk * 68 + ty * 4];
      float4 b4 = *(const float4*)&Bs[kk * 68 + tx * 4];
      float a[4] = {a4.x, a4.y, a4.z, a4.w};
      float b[4] = {b4.x, b4.y, b4.z, b4.w};
#pragma unroll
      for (int i = 0; i < 4; i++)
#pragma unroll
        for (int j = 0; j < 4; j++) acc[i][j] = fmaf(a[i], b[j], acc[i][j]);
    }
    __syncthreads();
  }
#pragma unroll
  for (int i = 0; i < 4; i++) {
    int r = row0 + ty * 4 + i;
    if (r >= n) continue;
#pragma unroll
    for (int j = 0; j < 4; j++) {
      int c = col0 + tx * 4 + j;
      float v = acc[i][j] + bias[c];
      if (OUTRELU) v = fmaxf(v, 0.f);
      out[(size_t)r * COUT + c] = v;
    }
  }
}

// ---- Paired variant: one dispatch computes both W0->out0 and W1->out1 ----
template <int CIN, bool BN, bool INRELU, bool OUTRELU>
__global__ void k_gemm_lin2(const float* __restrict__ X, const float* __restrict__ sc,
                            const float* __restrict__ sh,
                            const float* __restrict__ W0, const float* __restrict__ b0,
                            float* __restrict__ out0,
                            const float* __restrict__ W1, const float* __restrict__ b1,
                            float* __restrict__ out1, int n, int COUT, int colsPer) {
  __shared__ float As[32 * 68];
  __shared__ float Bs[32 * 68];
  int sel = blockIdx.y / colsPer;
  int col0 = (blockIdx.y - sel * colsPer) * 64;
  const float* W = sel ? W1 : W0;
  const float* bias = sel ? b1 : b0;
  float* out = sel ? out1 : out0;
  int t = threadIdx.x;
  int tx = t & 15, ty = t >> 4;
  int row0 = blockIdx.x * 64;
  float acc[4][4];
#pragma unroll
  for (int i = 0; i < 4; i++)
#pragma unroll
    for (int j = 0; j < 4; j++) acc[i][j] = 0.f;
  for (int k0 = 0; k0 < CIN; k0 += 32) {
    int kw = CIN - k0; if (kw > 32) kw = 32;
    for (int l = t; l < 64 * 32; l += 256) {
      int r = l >> 5, kk = l & 31;
      float v = 0.f;
      int rr = row0 + r;
      if (kk < kw && rr < n) {
        int k = k0 + kk;
        v = X[(size_t)rr * CIN + k];
        if (BN) v = fmaf(v, sc[k], sh[k]);
        if (INRELU) v = fmaxf(v, 0.f);
      }
      As[kk * 68 + r] = v;
    }
    for (int l = t; l < 32 * 64; l += 256) {
      int kk = l >> 6, cc = l & 63;
      Bs[kk * 68 + cc] = (kk < kw) ? W[(size_t)(k0 + kk) * COUT + col0 + cc] : 0.f;
    }
    __syncthreads();
#pragma unroll 8
    for (int kk = 0; kk < 32; kk++) {
      float4 a4 = *(const float4*)&As[kk * 68 + ty * 4];
      float4 b4 = *(const float4*)&Bs[kk * 68 + tx * 4];
      float a[4] = {a4.x, a4.y, a4.z, a4.w};
      float b[4] = {b4.x, b4.y, b4.z, b4.w};
#pragma unroll
      for (int i = 0; i < 4; i++)
#pragma unroll
        for (int j = 0; j < 4; j++) acc[i][j] = fmaf(a[i], b[j], acc[i][j]);
    }
    __syncthreads();
  }
#pragma unroll
  for (int i = 0; i < 4; i++) {
    int r = row0 + ty * 4 + i;
    if (r >= n) continue;
#pragma unroll
    for (int j = 0; j < 4; j++) {
      int c = col0 + tx * 4 + j;
      float v = acc[i][j] + bias[c];
      if (OUTRELU) v = fmaxf(v, 0.f);
      out[(size_t)r * COUT + c] = v;
    }
  }
}

// ---------------- CSR build ----------------
__global__ void k_hist(const int* __restrict__ dst, int E, int* __restrict__ cnt) {
  int e = blockIdx.x * 256 + threadIdx.x;
  if (e >= E) return;
  int d = dst[e];
  if (d >= 0 && d < NHIGH) atomicAdd(&cnt[d], 1);
}
__global__ void k_scan1(const int* __restrict__ cnt, int* __restrict__ rp,
                        int* __restrict__ part, int N) {
  __shared__ int sh[256];
  int i = blockIdx.x * 256 + threadIdx.x;
  int v = (i < N) ? cnt[i] : 0;
  sh[threadIdx.x] = v;
  __syncthreads();
  for (int off = 1; off < 256; off <<= 1) {
    int t = (threadIdx.x >= off) ? sh[threadIdx.x - off] : 0;
    __syncthreads();
    sh[threadIdx.x] += t;
    __syncthreads();
  }
  if (i < N) rp[i] = sh[threadIdx.x] - v;
  if (threadIdx.x == 255) part[blockIdx.x] = sh[255];
}
__global__ void k_scan2(int* __restrict__ part, int nb) {
  __shared__ int sh[256];
  int v = (threadIdx.x < nb) ? part[threadIdx.x] : 0;
  sh[threadIdx.x] = v;
  __syncthreads();
  for (int off = 1; off < 256; off <<= 1) {
    int t = (threadIdx.x >= off) ? sh[threadIdx.x - off] : 0;
    __syncthreads();
    sh[threadIdx.x] += t;
    __syncthreads();
  }
  if (threadIdx.x < nb) part[threadIdx.x] = sh[threadIdx.x] - v;
}
__global__ void k_scan3(int* __restrict__ rp, const int* __restrict__ part, int N, int E) {
  int i = blockIdx.x * 256 + threadIdx.x;
  if (i < N) rp[i] += part[i / 256];
  if (i == 0) rp[N] = E;
}
__global__ void k_csr_scatter(const int* __restrict__ src, const int* __restrict__ dst,
                              const int* __restrict__ rp, int* __restrict__ fil,
                              int* __restrict__ col, int E) {
  int e = blockIdx.x * 256 + threadIdx.x;
  if (e >= E) return;
  int d = dst[e];
  if (d < 0 || d >= NHIGH) return;
  int pos = rp[d] + atomicAdd(&fil[d], 1);
  if (pos >= 0 && pos < E) col[pos] = src[e];
}

// ---------------- Stage 2: bipartite GATv2, fused, no-max softmax, 2-edge unroll ----------------
__global__ void k_gat_th(const unsigned* __restrict__ hlu, const float* __restrict__ z,
                         const float* __restrict__ wr, const float* __restrict__ br,
                         const float* __restrict__ att, const int* __restrict__ rp,
                         const int* __restrict__ col, float* __restrict__ acc25) {
  int d = blockIdx.x, lane = threadIdx.x;
  int beg = rp[d];
  int deg = rp[d + 1] - beg;
  if (beg < 0) beg = 0;
  if (deg < 0) deg = 0;
  if (beg + deg > ELH) deg = (ELH - beg > 0) ? (ELH - beg) : 0;
  float zd = z[d];
  int g = lane >> 5, cc = lane & 31;
  bool act = cc < 25;
  int j0 = 50 * g + (act ? cc : 0), j1 = j0 + 25;
  float hrv0 = 0.f, atv0 = 0.f, hrv1 = 0.f, atv1 = 0.f;
  if (act) {
    hrv0 = fmaf(zd, wr[j0], br[j0]); atv0 = att[j0] * LOG2E;
    hrv1 = fmaf(zd, wr[j1], br[j1]); atv1 = att[j1] * LOG2E;
  }
  bool hi = (lane & 16) != 0;
  float den0 = 0.f, a0 = 0.f, den1 = 0.f, a1 = 0.f;
  int i = 0;
  for (; i + 2 <= deg; i += 2) {
    int sA = col[beg + i];
    int sB = col[beg + i + 1];
    if (sA < 0 || sA >= NL25) sA = 0;
    if (sB < 0 || sB >= NL25) sB = 0;
    unsigned uA = act ? hlu[(size_t)sA * 50 + g * 25 + cc] : 0u;
    unsigned uB = act ? hlu[(size_t)sB * 50 + g * 25 + cc] : 0u;
    float r0a = __uint_as_float(uA << 16), r1a = __uint_as_float(uA & 0xffff0000u);
    float r0b = __uint_as_float(uB << 16), r1b = __uint_as_float(uB & 0xffff0000u);
    float e0a = r0a + hrv0; e0a = (e0a > 0.f) ? e0a : 0.2f * e0a;
    float e1a = r1a + hrv1; e1a = (e1a > 0.f) ? e1a : 0.2f * e1a;
    float e0b = r0b + hrv0; e0b = (e0b > 0.f) ? e0b : 0.2f * e0b;
    float e1b = r1b + hrv1; e1b = (e1b > 0.f) ? e1b : 0.2f * e1b;
    float p0a = e0a * atv0, p1a = e1a * atv1;
    float p0b = e0b * atv0, p1b = e1b * atv1;
    float qa = (hi ? p1a : p0a) + __shfl_xor(hi ? p0a : p1a, 16, 64);
    float qb = (hi ? p1b : p0b) + __shfl_xor(hi ? p0b : p1b, 16, 64);
#pragma unroll
    for (int off = 8; off > 0; off >>= 1) {
      qa += __shfl_xor(qa, off, 64);
      qb += __shfl_xor(qb, off, 64);
    }
    float oa = __shfl_xor(qa, 16, 64);
    float ob = __shfl_xor(qb, 16, 64);
    p0a = hi ? oa : qa; p1a = hi ? qa : oa;
    p0b = hi ? ob : qb; p1b = hi ? qb : ob;
    float w0a = exp2f(p0a), w1a = exp2f(p1a);
    float w0b = exp2f(p0b), w1b = exp2f(p1b);
    den0 += w0a + w0b;
    den1 += w1a + w1b;
    a0 = fmaf(w0a, r0a, a0); a0 = fmaf(w0b, r0b, a0);
    a1 = fmaf(w1a, r1a, a1); a1 = fmaf(w1b, r1b, a1);
  }
  if (i < deg) {
    int s = col[beg + i];
    if (s < 0 || s >= NL25) s = 0;
    unsigned u = act ? hlu[(size_t)s * 50 + g * 25 + cc] : 0u;
    float r0 = __uint_as_float(u << 16);
    float r1 = __uint_as_float(u & 0xffff0000u);
    float e0 = r0 + hrv0; e0 = (e0 > 0.f) ? e0 : 0.2f * e0;
    float e1 = r1 + hrv1; e1 = (e1 > 0.f) ? e1 : 0.2f * e1;
    float p0 = e0 * atv0, p1 = e1 * atv1;
    float q = (hi ? p1 : p0) + __shfl_xor(hi ? p0 : p1, 16, 64);
#pragma unroll
    for (int off = 8; off > 0; off >>= 1) q += __shfl_xor(q, off, 64);
    float o = __shfl_xor(q, 16, 64);
    p0 = hi ? o : q;
    p1 = hi ? q : o;
    float w0 = exp2f(p0), w1 = exp2f(p1);
    den0 += w0; a0 = fmaf(w0, r0, a0);
    den1 += w1; a1 = fmaf(w1, r1, a1);
  }
  float v = a0 / fmaxf(den0, 1e-30f) + a1 / fmaxf(den1, 1e-30f);
  float other = __shfl_down(v, 32, 64);
  if (lane < 25) acc25[d * 25 + lane] = v + other;
}
__global__ void k_th_fin(const float* __restrict__ acc25, const int* __restrict__ rp,
                         const float* __restrict__ bias, const float* __restrict__ z,
                         float* __restrict__ x26) {
  int gid = blockIdx.x * 256 + threadIdx.x;
  int node = gid / 26, j = gid - node * 26;
  if (node >= NHIGH) return;
  if (j == 0) {
    x26[node * 26] = z[node];
  } else {
    int dg = rp[node + 1] - rp[node];
    if (dg < 1) dg = 1;
    x26[node * 26 + j] = acc25[node * 25 + j - 1] / (4.0f * (float)dg) + bias[j - 1];
  }
}

// ---------------- high-res GATv2: no-max softmax, 2-edge unroll, float2 channels ----------------
template <bool RELU>
__global__ void k_gat_hh2(const float* __restrict__ hl, const float* __restrict__ hr,
                          const float* __restrict__ att, const float* __restrict__ bias,
                          const int* __restrict__ rp, const int* __restrict__ col,
                          float* __restrict__ out) {
  const int F = 128;
  int d = blockIdx.x, lane = threadIdx.x;
  int h = lane >> 5, l2 = lane & 31;
  int c0 = h * 64 + 2 * l2;
  int beg = rp[d];
  int deg = rp[d + 1] - beg;
  if (beg < 0) beg = 0;
  if (deg < 0) deg = 0;
  if (beg + deg > EHH) deg = (EHH - beg > 0) ? (EHH - beg) : 0;
  int tot = deg + 1;  // + self loop
  float2 hrv = *(const float2*)&hr[(size_t)d * F + c0];
  float2 atv = *(const float2*)&att[c0];
  atv.x *= LOG2E; atv.y *= LOG2E;
  bool hi = (lane & 16) != 0;
  float den = 0.f, acc0 = 0.f, acc1 = 0.f;
  int i = 0;
  for (; i + 2 <= tot; i += 2) {
    int sA = (i < deg) ? col[beg + i] : d;
    int sB = (i + 1 < deg) ? col[beg + i + 1] : d;
    if (sA < 0 || sA >= NHIGH) sA = 0;
    if (sB < 0 || sB >= NHIGH) sB = 0;
    float2 ra = *(const float2*)&hl[(size_t)sA * F + c0];
    float2 rb = *(const float2*)&hl[(size_t)sB * F + c0];
    float e0a = ra.x + hrv.x; e0a = (e0a > 0.f) ? e0a : 0.2f * e0a;
    float e1a = ra.y + hrv.y; e1a = (e1a > 0.f) ? e1a : 0.2f * e1a;
    float pA = fmaf(e0a, atv.x, e1a * atv.y);
    float e0b = rb.x + hrv.x; e0b = (e0b > 0.f) ? e0b : 0.2f * e0b;
    float e1b = rb.y + hrv.y; e1b = (e1b > 0.f) ? e1b : 0.2f * e1b;
    float pB = fmaf(e0b, atv.x, e1b * atv.y);
    float own = hi ? pB : pA;
    float oth = hi ? pA : pB;
    float q = own + __shfl_xor(oth, 16, 64);
#pragma unroll
    for (int off = 8; off > 0; off >>= 1) q += __shfl_xor(q, off, 64);
    float o = __shfl_xor(q, 16, 64);
    pA = hi ? o : q;
    pB = hi ? q : o;
    float wA = exp2f(pA), wB = exp2f(pB);
    den += wA + wB;
    acc0 = fmaf(wA, ra.x, acc0); acc0 = fmaf(wB, rb.x, acc0);
    acc1 = fmaf(wA, ra.y, acc1); acc1 = fmaf(wB, rb.y, acc1);
  }
  if (i < tot) {
    int s = (i < deg) ? col[beg + i] : d;
    if (s < 0 || s >= NHIGH) s = 0;
    float2 r = *(const float2*)&hl[(size_t)s * F + c0];
    float e0 = r.x + hrv.x; e0 = (e0 > 0.f) ? e0 : 0.2f * e0;
    float e1 = r.y + hrv.y; e1 = (e1 > 0.f) ? e1 : 0.2f * e1;
    float p = fmaf(e0, atv.x, e1 * atv.y);
#pragma unroll
    for (int off = 16; off > 0; off >>= 1) p += __shfl_xor(p, off, 64);
    float w_ = exp2f(p);
    den += w_;
    acc0 = fmaf(w_, r.x, acc0);
    acc1 = fmaf(w_, r.y, acc1);
  }
  float inv = 1.0f / (fmaxf(den, 1e-30f) * (float)tot);
  float2 bv = *(const float2*)&bias[c0];
  float v0 = acc0 * inv + bv.x;
  float v1 = acc1 * inv + bv.y;
  if (RELU) { v0 = fmaxf(v0, 0.f); v1 = fmaxf(v1, 0.f); }
  *(float2*)&out[(size_t)d * F + c0] = make_float2(v0, v1);
}
template <bool RELU>
__global__ void k_gat_hh1(const float* __restrict__ hl, const float* __restrict__ hr,
                          const float* __restrict__ att, const float* __restrict__ bias,
                          const int* __restrict__ rp, const int* __restrict__ col,
                          float* __restrict__ out) {
  const int F = 64;
  int d = blockIdx.x, lane = threadIdx.x;
  int beg = rp[d];
  int deg = rp[d + 1] - beg;
  if (beg < 0) beg = 0;
  if (deg < 0) deg = 0;
  if (beg + deg > EHH) deg = (EHH - beg > 0) ? (EHH - beg) : 0;
  int tot = deg + 1;
  float hrv = hr[(size_t)d * F + lane];
  float atv = att[lane] * LOG2E;
  bool hi = lane >= 32;
  float den = 0.f, acc = 0.f;
  int i = 0;
  for (; i + 2 <= tot; i += 2) {
    int sA = (i < deg) ? col[beg + i] : d;
    int sB = (i + 1 < deg) ? col[beg + i + 1] : d;
    if (sA < 0 || sA >= NHIGH) sA = 0;
    if (sB < 0 || sB >= NHIGH) sB = 0;
    float rA = hl[(size_t)sA * F + lane];
    float rB = hl[(size_t)sB * F + lane];
    float eA = rA + hrv; eA = (eA > 0.f) ? eA : 0.2f * eA;
    float eB = rB + hrv; eB = (eB > 0.f) ? eB : 0.2f * eB;
    float pA = eA * atv, pB = eB * atv;
    float own = hi ? pB : pA;
    float oth = hi ? pA : pB;
    float q = own + __shfl_xor(oth, 32, 64);
#pragma unroll
    for (int off = 16; off > 0; off >>= 1) q += __shfl_xor(q, off, 64);
    float o = __shfl_xor(q, 32, 64);
    pA = hi ? o : q;
    pB = hi ? q : o;
    float wA = exp2f(pA), wB = exp2f(pB);
    den += wA + wB;
    acc = fmaf(wA, rA, acc);
    acc = fmaf(wB, rB, acc);
  }
  if (i < tot) {
    int s = (i < deg) ? col[beg + i] : d;
    if (s < 0 || s >= NHIGH) s = 0;
    float r = hl[(size_t)s * F + lane];
    float e = r + hrv; e = (e > 0.f) ? e : 0.2f * e;
    float p = e * atv;
#pragma unroll
    for (int off = 32; off > 0; off >>= 1) p += __shfl_xor(p, off, 64);
    float w_ = exp2f(p);
    den += w_;
    acc = fmaf(w_, r, acc);
  }
  float v = acc / (fmaxf(den, 1e-30f) * (float)tot) + bias[lane];
  if (RELU) v = fmaxf(v, 0.f);
  out[(size_t)d * F + lane] = v;
}

// ---------------- BatchNorm: parallel partials + f64 finalize -> scale/shift ----------------
__global__ void k_bn_part(const float* __restrict__ x, int C, int tpc,
                          float* __restrict__ ps, float* __restrict__ ps2) {
  int gch = blockIdx.x, t = threadIdx.x;
  int c = t % C, sub = t / C;
  float s = 0.f, s2 = 0.f;
  if (sub < tpc) {
    for (int r = gch * 500 + sub; r < gch * 500 + 500; r += tpc) {
      float v = x[(size_t)r * C + c];
      s += v;
      s2 = fmaf(v, v, s2);
    }
  }
  __shared__ float ls[256], ls2[256];
  ls[t] = s; ls2[t] = s2;
  __syncthreads();
  if (t < C) {
    float a = 0.f, a2 = 0.f;
    for (int u = 0; u < tpc; u++) { a += ls[u * C + t]; a2 += ls2[u * C + t]; }
    ps[gch * C + t] = a;
    ps2[gch * C + t] = a2;
  }
}
__global__ void k_bn_fin(const float* __restrict__ ps, const float* __restrict__ ps2,
                         int C, float n, const float* __restrict__ g,
                         const float* __restrict__ b, float* __restrict__ sc,
                         float* __restrict__ sh) {
  int c = blockIdx.x, t = threadIdx.x;
  __shared__ double ds[128], ds2[128];
  double a = 0, a2 = 0;
  for (int q = t; q < 100; q += 128) { a += ps[q * C + c]; a2 += ps2[q * C + c]; }
  ds[t] = a; ds2[t] = a2;
  __syncthreads();
  for (int off = 64; off > 0; off >>= 1) {
    if (t < off) { ds[t] += ds[t + off]; ds2[t] += ds2[t + off]; }
    __syncthreads();
  }
  if (t == 0) {
    double m = ds[0] / n;
    double v = ds2[0] / n - m * m;
    if (v < 0) v = 0;
    float scale = g[c] * rsqrtf((float)v + 1e-5f);
    sc[c] = scale;
    sh[c] = b[c] - (float)m * scale;
  }
}

// small naive linear for MLP tails
template <int CIN, int COUT, bool RELU>
__global__ void k_linear(const float* __restrict__ x, const float* __restrict__ W,
                         const float* __restrict__ b, float* __restrict__ y, int n) {
  long long gid = (long long)blockIdx.x * 256 + threadIdx.x;
  int node = (int)(gid / COUT);
  int j = (int)(gid - (long long)node * COUT);
  if (node >= n) return;
  const float* xr = x + (size_t)node * CIN;
  float acc = b[j];
#pragma unroll 4
  for (int k = 0; k < CIN; k++) acc = fmaf(xr[k], W[k * COUT + j], acc);
  if (RELU) acc = fmaxf(acc, 0.f);
  y[(size_t)node * COUT + j] = acc;
}

extern "C" void kernel_launch(void* const* d_in, const int* in_sizes, int n_in,
                              void* d_out, int out_size, void* d_ws, size_t ws_size,
                              hipStream_t stream) {
  auto nb = [](long long t) { return dim3((unsigned)((t + 255) / 256)); };
  static const int FSZ[38] = {
      1000000, 50000, 78125, 3125, 12500, 100, 100, 100, 100, 25, 26, 26,
      3328, 128, 3328, 128, 128, 128, 512, 512, 49152, 384, 49152, 384, 384,
      384, 8192, 64, 8192, 64, 64, 64, 4096, 64, 2048, 32, 32, 1};
  static const int ISZ[4] = {64000, 1250000, 1250000, 1600000};
  if (n_in != 42) {
    k_fill_out<<<nb(out_size), 256, 0, stream>>>((float*)d_out, out_size, 500000.0f);
    return;
  }
  bool szok = true;
  for (int i = 0; i < 38; i++) szok &= (in_sizes[i] == FSZ[i]);
  for (int i = 0; i < 4; i++) szok &= (in_sizes[38 + i] == ISZ[i]);
  if (!szok) {
    k_fill_out<<<nb(out_size), 256, 0, stream>>>((float*)d_out, out_size, 600000.0f);
    return;
  }
  const size_t REQUIRED = 20146000ull * 4ull;
  if (ws_size < REQUIRED) {
    hipMemsetAsync(d_out, 0, (size_t)out_size * 4, stream);
    return;
  }

  const float* w[38];
  for (int i = 0; i < 38; i++) w[i] = (const float*)d_in[i];  // f32 (verified r6/r9)
  const int* ei_ll = (const int*)d_in[38];  // int32 (verified r9/r10)
  const int* s_l2h = (const int*)d_in[39];
  const int* d_l2h = (const int*)d_in[40];
  const int* ei_hh = (const int*)d_in[41];

  float* ws = (float*)d_ws;
  float* S0 = ws;                       // [0, 6.4M)
  float* S1 = ws + 6400000;             // [6.4M, 12.8M)
  float* S2 = ws + 12800000;            // [12.8M, 19.2M)
  unsigned short* hl100 = (unsigned short*)ws;  // [20M bf16] = 10M words
  float* acc25 = ws + 10000000;         // [1,250,000]
  int*  rpT  = (int*)(ws + 11300000);   // [50,001]
  int*  filT = (int*)(ws + 11360000);   // [50,000]
  int*  colT = (int*)(ws + 11450000);   // [1,250,000] -> 12.7M
  float* xa  = ws + 12800000;           // [1,000,000]
  float* Mt  = ws + 13800000;           // [312,500]
  float* b2  = ws + 14112500;           // [2,500]
  float* x26 = ws + 14200000;           // [1,300,000] (dead before S2 written)
  int*  rpH  = (int*)(ws + 19200000);   // [50,001]
  int*  filH = (int*)(ws + 19260000);   // [50,000]
  int*  colH = (int*)(ws + 19310000);   // [800,000] -> 20,110,000
  float* deg = ws + 20110000;           // [8,000]
  float* sc  = ws + 20118000;           // [128]
  float* sh  = ws + 20118128;           // [128]
  int*  part = (int*)(ws + 20118256);   // [512]
  float* ps   = ws + 20120000;          // [12,800]
  float* ps2  = ws + 20132800;          // [12,800] -> 20,145,600

  // ---- CSR for both graphs ----
  auto build_csr = [&](const int* src, const int* dst, int E, int* rp, int* fil,
                       int* col) {
    hipMemsetAsync(fil, 0, NHIGH * 4, stream);
    k_hist<<<nb(E), 256, 0, stream>>>(dst, E, fil);
    int nblk = (NHIGH + 255) / 256;
    k_scan1<<<nblk, 256, 0, stream>>>(fil, rp, part, NHIGH);
    k_scan2<<<1, 256, 0, stream>>>(part, nblk);
    k_scan3<<<nb(NHIGH), 256, 0, stream>>>(rp, part, NHIGH, E);
    hipMemsetAsync(fil, 0, NHIGH * 4, stream);
    k_csr_scatter<<<nb(E), 256, 0, stream>>>(src, dst, rp, fil, col, E);
  };
  build_csr(s_l2h, d_l2h, ELH, rpT, filT, colT);
  build_csr(ei_hh, ei_hh + EHH, EHH, rpH, filH, colH);

  // ---- Stage 1: GCN fold ----
  k_init_deg<<<nb(NLOW), 256, 0, stream>>>(deg);
  k_gcn_deg<<<nb(ELL), 256, 0, stream>>>(ei_ll, deg);
  k_xa_init<<<nb(NLOW * 125), 256, 0, stream>>>(w[0], deg, xa);
  k_xa_edge<<<nb((long long)ELL * 125), 256, 0, stream>>>(w[0], ei_ll, deg, xa);
  k_prep_M<<<nb(125 * 2500), 256, 0, stream>>>(w[2], w[4], Mt);
  k_prep_b2<<<nb(2500), 256, 0, stream>>>(w[3], w[4], w[5], b2);

  // ---- Stage 2: th GATv2, single fused pass ----
  k_hlT_gemm<<<dim3(125, 40), 256, 0, stream>>>(xa, Mt, b2, hl100);
  k_gat_th<<<NHIGH, 64, 0, stream>>>((const unsigned*)hl100, w[1], w[6], w[7], w[8],
                                     rpT, colT, acc25);
  k_th_fin<<<nb((long long)NHIGH * 26), 256, 0, stream>>>(acc25, rpT, w[9], w[1], x26);

  // ---- Stage 3: bn0 + g1 ----
  k_bn_part<<<100, 256, 0, stream>>>(x26, 26, 9, ps, ps2);
  k_bn_fin<<<26, 128, 0, stream>>>(ps, ps2, 26, (float)NHIGH, w[10], w[11], sc, sh);
  k_gemm_lin2<26, true, false, false><<<dim3(782, 4), 256, 0, stream>>>(
      x26, sc, sh, w[12], w[13], S0, w[14], w[15], S1, NHIGH, 128, 2);
  k_gat_hh2<false><<<NHIGH, 64, 0, stream>>>(S0, S1, w[16], w[17], rpH, colH, S2);

  // ---- Stage 4: 3x gm ----
  for (int i = 0; i < 3; i++) {
    k_bn_part<<<100, 256, 0, stream>>>(S2, 128, 2, ps, ps2);
    k_bn_fin<<<128, 128, 0, stream>>>(ps, ps2, 128, (float)NHIGH, w[18] + i * 128,
                                      w[19] + i * 128, sc, sh);
    k_gemm_lin2<128, true, true, false><<<dim3(782, 4), 256, 0, stream>>>(
        S2, sc, sh, w[20] + i * 16384, w[21] + i * 128, S0,
        w[22] + i * 16384, w[23] + i * 128, S1, NHIGH, 128, 2);
    k_gat_hh2<false><<<NHIGH, 64, 0, stream>>>(S0, S1, w[24] + i * 128,
                                               w[25] + i * 128, rpH, colH, S2);
  }

  // ---- Stage 5: g5 ----
  k_bn_part<<<100, 256, 0, stream>>>(S2, 128, 2, ps, ps2);
  k_bn_fin<<<128, 128, 0, stream>>>(ps, ps2, 128, (float)NHIGH, w[18] + 384,
                                    w[19] + 384, sc, sh);
  k_gemm_lin2<128, true, true, false><<<dim3(782, 2), 256, 0, stream>>>(
      S2, sc, sh, w[26], w[27], S0, w[28], w[29], S1, NHIGH, 64, 1);
  k_gat_hh1<true><<<NHIGH, 64, 0, stream>>>(S0, S1, w[30], w[31], rpH, colH, S2);

  // ---- Stage 6: MLP ----
  k_gemm_lin<64, false, false, true><<<dim3(782, 1), 256, 0, stream>>>(
      S2, sc, sh, w[32], w[33], S0, NHIGH, 64);
  k_linear<64, 32, true><<<nb((long long)NHIGH * 32), 256, 0, stream>>>(
      S0, w[34], w[35], S1, NHIGH);
  k_linear<32, 1, false><<<nb((long long)NHIGH), 256, 0, stream>>>(
      S1, w[36], w[37], (float*)d_out, NHIGH);
}